// Round 1
// baseline (2944.144 us; speedup 1.0000x reference)
//
#include <hip/hip_runtime.h>
#include <hip/hip_bf16.h>
#include <math.h>

// ---------------------------------------------------------------------------
// RotaryAttention baseline (fp32, VALU). Round 1.
// Stages: [rope table] -> [3x proj GEMM -> head-major] -> [rope inplace]
//         -> [flash attn inplace over Q buffer] -> [output GEMM -> d_out]
// ws layout: Q (33.5MB) | K (33.5MB) | V (33.5MB) | cos/sin table (1MB)
// ---------------------------------------------------------------------------

#define D_MODEL 2048
#define NHEADS  16
#define DK      128
#define BATCH   2
#define SEQ     2048
#define MTOT    (BATCH*SEQ)   // 4096

// ---------------- RoPE cos/sin table: cs[s*64+j] = {cos,sin}(s * 10000^(-j/64))
__global__ void rope_table_kernel(float2* __restrict__ cs) {
    int idx = blockIdx.x * blockDim.x + threadIdx.x;
    if (idx >= SEQ * 64) return;
    int s = idx >> 6, j = idx & 63;
    double inv = pow(10000.0, -(double)j / 64.0);
    double f = (double)s * inv;
    cs[idx] = make_float2((float)cos(f), (float)sin(f));
}

// ---------------- fp32 GEMM: C[M][N] = A[M][K] * W[N][K]^T + bias[N]
// AMODE 0: A row-major [M][K].  AMODE 1: A head-major [B][H][S][DK] (m=b*S+s, k=h*DK+d)
// CMODE 0: C row-major [M][N].  CMODE 1: C head-major [B][H][S][DK] (n=h*DK+d)
#define BM 128
#define BN 128
#define BKSTEP 16

template<int AMODE, int CMODE>
__global__ __launch_bounds__(256, 2)
void gemm_nt_kernel(const float* __restrict__ A, const float* __restrict__ W,
                    const float* __restrict__ bias, float* __restrict__ C,
                    int M, int N, int K) {
    __shared__ float As[BKSTEP][BM + 4];
    __shared__ float Bs[BKSTEP][BN + 4];
    const int tid = threadIdx.x;
    const int tx = tid & 15, ty = tid >> 4;
    const int m0 = blockIdx.x * BM;
    const int n0 = blockIdx.y * BN;

    float c[8][8];
    #pragma unroll
    for (int i = 0; i < 8; ++i)
        #pragma unroll
        for (int j = 0; j < 8; ++j) c[i][j] = 0.f;

    for (int k0 = 0; k0 < K; k0 += BKSTEP) {
        // ---- load A tile (128 rows x 16 cols), store transposed As[k][m]
        #pragma unroll
        for (int it = 0; it < 2; ++it) {
            int f = it * 256 + tid;
            int r = f >> 2, c4 = f & 3;
            const float* src;
            if (AMODE == 0) {
                src = A + (size_t)(m0 + r) * K + k0 + c4 * 4;
            } else {
                int m = m0 + r;
                int b = m >> 11;            // m / SEQ
                int s = m & 2047;           // m % SEQ
                int h = k0 >> 7;            // k0 / DK (BKSTEP=16 divides DK)
                int d = (k0 & 127) + c4 * 4;
                src = A + (((size_t)(b * NHEADS + h)) * SEQ + s) * DK + d;
            }
            float4 v = *(const float4*)src;
            As[c4 * 4 + 0][r] = v.x;
            As[c4 * 4 + 1][r] = v.y;
            As[c4 * 4 + 2][r] = v.z;
            As[c4 * 4 + 3][r] = v.w;
        }
        // ---- load W tile (128 rows x 16 cols), store transposed Bs[k][n]
        #pragma unroll
        for (int it = 0; it < 2; ++it) {
            int f = it * 256 + tid;
            int r = f >> 2, c4 = f & 3;
            float4 v = *(const float4*)(W + (size_t)(n0 + r) * K + k0 + c4 * 4);
            Bs[c4 * 4 + 0][r] = v.x;
            Bs[c4 * 4 + 1][r] = v.y;
            Bs[c4 * 4 + 2][r] = v.z;
            Bs[c4 * 4 + 3][r] = v.w;
        }
        __syncthreads();
        #pragma unroll
        for (int k = 0; k < BKSTEP; ++k) {
            float4 a0 = *(const float4*)&As[k][ty * 4];
            float4 a1 = *(const float4*)&As[k][64 + ty * 4];
            float4 b0 = *(const float4*)&Bs[k][tx * 4];
            float4 b1 = *(const float4*)&Bs[k][64 + tx * 4];
            float av[8] = {a0.x, a0.y, a0.z, a0.w, a1.x, a1.y, a1.z, a1.w};
            float bv[8] = {b0.x, b0.y, b0.z, b0.w, b1.x, b1.y, b1.z, b1.w};
            #pragma unroll
            for (int i = 0; i < 8; ++i)
                #pragma unroll
                for (int j = 0; j < 8; ++j)
                    c[i][j] = fmaf(av[i], bv[j], c[i][j]);
        }
        __syncthreads();
    }

    // ---- epilogue: + bias, store
    float4 bia0 = *(const float4*)(bias + n0 + tx * 4);
    float4 bia1 = *(const float4*)(bias + n0 + 64 + tx * 4);
    float bv[8] = {bia0.x, bia0.y, bia0.z, bia0.w, bia1.x, bia1.y, bia1.z, bia1.w};
    #pragma unroll
    for (int i = 0; i < 8; ++i) {
        int mrow = m0 + ((i < 4) ? (ty * 4 + i) : (64 + ty * 4 + i - 4));
        float4 v0 = make_float4(c[i][0] + bv[0], c[i][1] + bv[1],
                                c[i][2] + bv[2], c[i][3] + bv[3]);
        float4 v1 = make_float4(c[i][4] + bv[4], c[i][5] + bv[5],
                                c[i][6] + bv[6], c[i][7] + bv[7]);
        if (CMODE == 0) {
            float* dst = C + (size_t)mrow * N + n0;
            *(float4*)(dst + tx * 4) = v0;
            *(float4*)(dst + 64 + tx * 4) = v1;
        } else {
            int b = mrow >> 11, s = mrow & 2047;
            int h = n0 >> 7;
            float* dst = C + (((size_t)(b * NHEADS + h)) * SEQ + s) * DK;
            *(float4*)(dst + tx * 4) = v0;
            *(float4*)(dst + 64 + tx * 4) = v1;
        }
    }
}

// ---------------- in-place RoPE on Q and K (head-major [B][H][S][DK])
__global__ void rope_kernel(float* __restrict__ Q, float* __restrict__ Kt,
                            const float2* __restrict__ cs) {
    int idx = blockIdx.x * blockDim.x + threadIdx.x;   // over B*H*S*64
    if (idx >= BATCH * NHEADS * SEQ * 64) return;
    int d = idx & 63;
    int bhs = idx >> 6;
    int s = bhs & (SEQ - 1);                            // layout [b][h][s]
    float2 c = cs[(s << 6) + d];
    size_t base = (size_t)bhs * DK;
    float q0 = Q[base + d], q1 = Q[base + d + 64];
    Q[base + d]      = q0 * c.x - q1 * c.y;
    Q[base + d + 64] = q1 * c.x + q0 * c.y;
    float k0 = Kt[base + d], k1 = Kt[base + d + 64];
    Kt[base + d]      = k0 * c.x - k1 * c.y;
    Kt[base + d + 64] = k1 * c.x + k0 * c.y;
}

// ---------------- fp32 flash attention, head-major panels; O overwrites Q panel
#define QT 64
#define KT 32

__global__ __launch_bounds__(256, 2)
void attn_kernel(float* __restrict__ Q,            // in: Q, out: O (in-place)
                 const float* __restrict__ Kp,
                 const float* __restrict__ Vp) {
    __shared__ float Qs[QT][DK + 4];     // 33.8 KB (Q pre-scaled by 1/sqrt(DK))
    __shared__ float KVs[KT][DK + 4];    // 16.9 KB (K tile, then V tile)
    __shared__ float Ps[QT][KT + 4];     //  9.2 KB
    const int tid = threadIdx.x;
    const int tx = tid & 15, ty = tid >> 4;
    const int qt = blockIdx.x;
    const int bh = blockIdx.y;
    float* qpanel = Q + (size_t)bh * SEQ * DK;
    const float* kpanel = Kp + (size_t)bh * SEQ * DK;
    const float* vpanel = Vp + (size_t)bh * SEQ * DK;
    const int q0 = qt * QT;
    const float scale = 0.08838834764831845f;   // 1/sqrt(128)

    // load Q tile (scaled)
    #pragma unroll
    for (int it = 0; it < 8; ++it) {
        int f = it * 256 + tid;
        int r = f >> 5, c4 = f & 31;
        float4 v = *(const float4*)(qpanel + (size_t)(q0 + r) * DK + c4 * 4);
        v.x *= scale; v.y *= scale; v.z *= scale; v.w *= scale;
        *(float4*)&Qs[r][c4 * 4] = v;
    }

    float m_i[4], l_i[4], acc[4][8];
    #pragma unroll
    for (int i = 0; i < 4; ++i) {
        m_i[i] = -1e30f; l_i[i] = 0.f;
        #pragma unroll
        for (int j = 0; j < 8; ++j) acc[i][j] = 0.f;
    }

    for (int kv0 = 0; kv0 < SEQ; kv0 += KT) {
        __syncthreads();                          // prev PV / P reads done
        // load K tile
        #pragma unroll
        for (int it = 0; it < 4; ++it) {
            int f = it * 256 + tid;
            int r = f >> 5, c4 = f & 31;
            *(float4*)&KVs[r][c4 * 4] =
                *(const float4*)(kpanel + (size_t)(kv0 + r) * DK + c4 * 4);
        }
        __syncthreads();

        // scores: thread owns q rows ty*4+i, k cols {tx, 16+tx}
        float sc[4][2];
        #pragma unroll
        for (int i = 0; i < 4; ++i) { sc[i][0] = 0.f; sc[i][1] = 0.f; }
        #pragma unroll 4
        for (int d4 = 0; d4 < 32; ++d4) {
            float4 k0v = *(const float4*)&KVs[tx][d4 * 4];
            float4 k1v = *(const float4*)&KVs[16 + tx][d4 * 4];
            #pragma unroll
            for (int i = 0; i < 4; ++i) {
                float4 qv = *(const float4*)&Qs[ty * 4 + i][d4 * 4];
                sc[i][0] = fmaf(qv.x, k0v.x, sc[i][0]);
                sc[i][0] = fmaf(qv.y, k0v.y, sc[i][0]);
                sc[i][0] = fmaf(qv.z, k0v.z, sc[i][0]);
                sc[i][0] = fmaf(qv.w, k0v.w, sc[i][0]);
                sc[i][1] = fmaf(qv.x, k1v.x, sc[i][1]);
                sc[i][1] = fmaf(qv.y, k1v.y, sc[i][1]);
                sc[i][1] = fmaf(qv.z, k1v.z, sc[i][1]);
                sc[i][1] = fmaf(qv.w, k1v.w, sc[i][1]);
            }
        }

        // online softmax update (row lives in 16 lanes: shfl_xor 1,2,4,8)
        #pragma unroll
        for (int i = 0; i < 4; ++i) {
            float mx = fmaxf(sc[i][0], sc[i][1]);
            #pragma unroll
            for (int off = 1; off <= 8; off <<= 1)
                mx = fmaxf(mx, __shfl_xor(mx, off, 64));
            float mnew = fmaxf(m_i[i], mx);
            float corr = __expf(m_i[i] - mnew);
            float p0 = __expf(sc[i][0] - mnew);
            float p1 = __expf(sc[i][1] - mnew);
            float rowsum = p0 + p1;
            #pragma unroll
            for (int off = 1; off <= 8; off <<= 1)
                rowsum += __shfl_xor(rowsum, off, 64);
            l_i[i] = l_i[i] * corr + rowsum;
            m_i[i] = mnew;
            #pragma unroll
            for (int j = 0; j < 8; ++j) acc[i][j] *= corr;
            Ps[ty * 4 + i][tx] = p0;
            Ps[ty * 4 + i][16 + tx] = p1;
        }
        __syncthreads();                          // K reads + P writes done
        // load V tile into same buffer
        #pragma unroll
        for (int it = 0; it < 4; ++it) {
            int f = it * 256 + tid;
            int r = f >> 5, c4 = f & 31;
            *(float4*)&KVs[r][c4 * 4] =
                *(const float4*)(vpanel + (size_t)(kv0 + r) * DK + c4 * 4);
        }
        __syncthreads();

        // PV: acc[i][0..3] = d tx*4.., acc[i][4..7] = d 64+tx*4..
        #pragma unroll
        for (int kk = 0; kk < 8; ++kk) {
            float4 p4[4];
            #pragma unroll
            for (int i = 0; i < 4; ++i)
                p4[i] = *(const float4*)&Ps[ty * 4 + i][kk * 4];
            #pragma unroll
            for (int j = 0; j < 4; ++j) {
                float4 v0 = *(const float4*)&KVs[kk * 4 + j][tx * 4];
                float4 v1 = *(const float4*)&KVs[kk * 4 + j][64 + tx * 4];
                #pragma unroll
                for (int i = 0; i < 4; ++i) {
                    float p = (j == 0) ? p4[i].x : (j == 1) ? p4[i].y
                            : (j == 2) ? p4[i].z : p4[i].w;
                    acc[i][0] = fmaf(p, v0.x, acc[i][0]);
                    acc[i][1] = fmaf(p, v0.y, acc[i][1]);
                    acc[i][2] = fmaf(p, v0.z, acc[i][2]);
                    acc[i][3] = fmaf(p, v0.w, acc[i][3]);
                    acc[i][4] = fmaf(p, v1.x, acc[i][4]);
                    acc[i][5] = fmaf(p, v1.y, acc[i][5]);
                    acc[i][6] = fmaf(p, v1.z, acc[i][6]);
                    acc[i][7] = fmaf(p, v1.w, acc[i][7]);
                }
            }
        }
    }

    // normalize + write O over Q panel (block's own rows only: safe)
    #pragma unroll
    for (int i = 0; i < 4; ++i) {
        float inv = 1.0f / l_i[i];
        float* dst = qpanel + (size_t)(q0 + ty * 4 + i) * DK;
        float4 o0 = make_float4(acc[i][0] * inv, acc[i][1] * inv,
                                acc[i][2] * inv, acc[i][3] * inv);
        float4 o1 = make_float4(acc[i][4] * inv, acc[i][5] * inv,
                                acc[i][6] * inv, acc[i][7] * inv);
        *(float4*)(dst + tx * 4) = o0;
        *(float4*)(dst + 64 + tx * 4) = o1;
    }
}

// ---------------------------------------------------------------------------
extern "C" void kernel_launch(void* const* d_in, const int* in_sizes, int n_in,
                              void* d_out, int out_size, void* d_ws, size_t ws_size,
                              hipStream_t stream) {
    const float* x   = (const float*)d_in[0];
    const float* w_q = (const float*)d_in[1];
    const float* b_q = (const float*)d_in[2];
    const float* w_k = (const float*)d_in[3];
    const float* b_k = (const float*)d_in[4];
    const float* w_v = (const float*)d_in[5];
    const float* b_v = (const float*)d_in[6];
    const float* w_o = (const float*)d_in[7];
    const float* b_o = (const float*)d_in[8];
    float* out = (float*)d_out;

    char* ws = (char*)d_ws;
    const size_t tensorBytes = (size_t)BATCH * NHEADS * SEQ * DK * sizeof(float); // 33.5MB
    float*  Qb = (float*)(ws);
    float*  Kb = (float*)(ws + tensorBytes);
    float*  Vb = (float*)(ws + 2 * tensorBytes);
    float2* cs = (float2*)(ws + 3 * tensorBytes);
    // requires ws_size >= ~102MB

    rope_table_kernel<<<(SEQ * 64 + 255) / 256, 256, 0, stream>>>(cs);

    dim3 ggrid(MTOT / BM, D_MODEL / BN);
    gemm_nt_kernel<0, 1><<<ggrid, 256, 0, stream>>>(x, w_q, b_q, Qb, MTOT, D_MODEL, D_MODEL);
    gemm_nt_kernel<0, 1><<<ggrid, 256, 0, stream>>>(x, w_k, b_k, Kb, MTOT, D_MODEL, D_MODEL);
    gemm_nt_kernel<0, 1><<<ggrid, 256, 0, stream>>>(x, w_v, b_v, Vb, MTOT, D_MODEL, D_MODEL);

    rope_kernel<<<(BATCH * NHEADS * SEQ * 64 + 255) / 256, 256, 0, stream>>>(Qb, Kb, cs);

    attn_kernel<<<dim3(SEQ / QT, BATCH * NHEADS), 256, 0, stream>>>(Qb, Kb, Vb);

    gemm_nt_kernel<1, 0><<<ggrid, 256, 0, stream>>>(Qb, w_o, b_o, out, MTOT, D_MODEL, D_MODEL);
}

// Round 5
// 722.200 us; speedup vs baseline: 4.0766x; 4.0766x over previous
//
#include <hip/hip_runtime.h>
#include <hip/hip_bf16.h>
#include <math.h>

// ---------------------------------------------------------------------------
// Round 5: bf16-MFMA GEMMs (m97 structure) + bf16-MFMA flash attention
// (4 waves x 16 q-rows, KT=32, XOR-swizzled K LDS, f32 Vt/Ps LDS, fp32
// online softmax identical reduction to the round-1-validated kernel).
// ws: Qbf | Kbf | Vbf | Xbf | Wbf(4) | cs  == 101,711,872 B
// ---------------------------------------------------------------------------

#define D_MODEL 2048
#define NHEADS  16
#define DK      128
#define BATCH   2
#define SEQ     2048
#define MTOT    (BATCH*SEQ)            // 4096
#define XN      (MTOT*D_MODEL)         // 8,388,608
#define WN      (D_MODEL*D_MODEL)      // 4,194,304

typedef __attribute__((ext_vector_type(8))) short bf16x8;
typedef __attribute__((ext_vector_type(4))) float f32x4;
typedef __attribute__((ext_vector_type(8))) unsigned short u16x8;

__device__ __forceinline__ float bf2f(unsigned short u) {
    union { unsigned int i; float f; } v; v.i = ((unsigned int)u) << 16; return v.f;
}
__device__ __forceinline__ unsigned short f2bfu(float f) {
    __hip_bfloat16 h = __float2bfloat16(f);   // RNE
    return *reinterpret_cast<unsigned short*>(&h);
}
__device__ __forceinline__ void async_copy16(const unsigned short* g, unsigned short* l) {
    __builtin_amdgcn_global_load_lds((const __attribute__((address_space(1))) void*)g,
                                     (__attribute__((address_space(3))) void*)l, 16, 0, 0);
}

// ---------------- RoPE cos/sin table
__global__ void rope_table_kernel(float2* __restrict__ cs) {
    int idx = blockIdx.x * blockDim.x + threadIdx.x;
    if (idx >= SEQ * 64) return;
    int s = idx >> 6, j = idx & 63;
    double inv = pow(10000.0, -(double)j / 64.0);
    double f = (double)s * inv;
    cs[idx] = make_float2((float)cos(f), (float)sin(f));
}

// ---------------- fp32 -> bf16 conversion of x and the 4 weights
__global__ void convert_kernel(const float* __restrict__ x,
                               const float* __restrict__ wq, const float* __restrict__ wk,
                               const float* __restrict__ wv, const float* __restrict__ wo,
                               unsigned short* __restrict__ Xbf, unsigned short* __restrict__ Wbf) {
    size_t e = ((size_t)blockIdx.x * blockDim.x + threadIdx.x) * 4;
    const float* src; unsigned short* dst;
    if (e < XN) { src = x + e; dst = Xbf + e; }
    else {
        size_t r = e - XN; int w = (int)(r >> 22); size_t o = r & (WN - 1);
        src = (w == 0 ? wq : w == 1 ? wk : w == 2 ? wv : wo) + o;
        dst = Wbf + (size_t)w * WN + o;
    }
    float4 v = *(const float4*)src;
    ushort4 u;
    u.x = f2bfu(v.x); u.y = f2bfu(v.y); u.z = f2bfu(v.z); u.w = f2bfu(v.w);
    *(ushort4*)dst = u;
}

// ---------------- bf16 MFMA GEMM: C[M=4096][N=2048] = A*W^T + bias, K=2048
// AMODE 0: A row-major bf16 [M][K].  AMODE 1: A head-major bf16 [B][H][S][DK].
// CMODE 0: C fp32 row-major.        CMODE 1: C bf16 head-major.
#define BM 128
#define BN 128
#define BK 32

template<int AMODE, int CMODE>
__global__ __launch_bounds__(256, 2)
void gemm_bf16_kernel(const unsigned short* __restrict__ A,
                      const unsigned short* __restrict__ W,
                      const float* __restrict__ bias, void* __restrict__ Cout) {
    __shared__ unsigned short smem[8192];   // As[128][32] | Bs[128][32]
    const int tid = threadIdx.x;
    const int lane = tid & 63, wid = tid >> 6;
    const int wm = wid >> 1, wn = wid & 1;
    const int m0 = blockIdx.x * BM, n0 = blockIdx.y * BN;

    f32x4 acc[4][4];
    #pragma unroll
    for (int i = 0; i < 4; ++i)
        #pragma unroll
        for (int j = 0; j < 4; ++j) acc[i][j] = (f32x4){0.f, 0.f, 0.f, 0.f};

    const int lrow = lane & 15, lkc = lane >> 4;

    for (int k0 = 0; k0 < D_MODEL; k0 += BK) {
        #pragma unroll
        for (int i = 0; i < 4; ++i) {
            const int off = i * 4096 + wid * 1024 + lane * 16;   // byte in 16KB tile-pair
            const unsigned short* src;
            if (i < 2) {                          // A region [0,8192)
                int elem = off >> 1, row = elem >> 5, col = elem & 31;
                if (AMODE == 0) {
                    src = A + (size_t)(m0 + row) * D_MODEL + k0 + col;
                } else {
                    int m = m0 + row, b = m >> 11, s = m & 2047;
                    src = A + (((size_t)(b * NHEADS + (k0 >> 7))) * SEQ + s) * DK + (k0 & 127) + col;
                }
            } else {                              // B region
                int elem = (off - 8192) >> 1, row = elem >> 5, col = elem & 31;
                src = W + (size_t)(n0 + row) * D_MODEL + k0 + col;
            }
            async_copy16(src, &smem[(i * 4096 + wid * 1024) >> 1]);  // wave-uniform dest
        }
        __syncthreads();

        bf16x8 a[4], b[4];
        #pragma unroll
        for (int mi = 0; mi < 4; ++mi)
            a[mi] = *(const bf16x8*)&smem[(wm * 64 + mi * 16 + lrow) * 32 + lkc * 8];
        #pragma unroll
        for (int ni = 0; ni < 4; ++ni)
            b[ni] = *(const bf16x8*)&smem[4096 + (wn * 64 + ni * 16 + lrow) * 32 + lkc * 8];
        #pragma unroll
        for (int mi = 0; mi < 4; ++mi)
            #pragma unroll
            for (int ni = 0; ni < 4; ++ni)
                acc[mi][ni] = __builtin_amdgcn_mfma_f32_16x16x32_bf16(a[mi], b[ni], acc[mi][ni], 0, 0, 0);
        __syncthreads();
    }

    // epilogue: C/D layout col=lane&15, row=(lane>>4)*4+r  [m89-verified]
    const int lq = lane >> 4;
    #pragma unroll
    for (int ni = 0; ni < 4; ++ni) {
        int col = n0 + wn * 64 + ni * 16 + lrow;
        float bv = bias[col];
        #pragma unroll
        for (int mi = 0; mi < 4; ++mi) {
            #pragma unroll
            for (int r = 0; r < 4; ++r) {
                int row = m0 + wm * 64 + mi * 16 + lq * 4 + r;
                float v = acc[mi][ni][r] + bv;
                if (CMODE == 0) {
                    ((float*)Cout)[(size_t)row * D_MODEL + col] = v;
                } else {
                    int bb = row >> 11, s = row & 2047, h = col >> 7, d = col & 127;
                    ((unsigned short*)Cout)[(((size_t)(bb * NHEADS + h)) * SEQ + s) * DK + d] = f2bfu(v);
                }
            }
        }
    }
}

// ---------------- in-place RoPE on bf16 Q and K (head-major)
__global__ void rope_kernel(unsigned short* __restrict__ Q, unsigned short* __restrict__ Kt,
                            const float2* __restrict__ cs) {
    int idx = blockIdx.x * blockDim.x + threadIdx.x;   // B*H*S*8
    if (idx >= BATCH * NHEADS * SEQ * 8) return;
    int j8 = idx & 7, bhs = idx >> 3, s = bhs & (SEQ - 1);
    int d0 = j8 * 8;
    size_t base = (size_t)bhs * DK;
    u16x8 qlo = *(const u16x8*)(Q + base + d0);
    u16x8 qhi = *(const u16x8*)(Q + base + 64 + d0);
    u16x8 klo = *(const u16x8*)(Kt + base + d0);
    u16x8 khi = *(const u16x8*)(Kt + base + 64 + d0);
    u16x8 olo, ohi, plo, phi;
    #pragma unroll
    for (int j = 0; j < 8; ++j) {
        float2 c = cs[(s << 6) + d0 + j];
        float q0 = bf2f(qlo[j]), q1 = bf2f(qhi[j]);
        olo[j] = f2bfu(q0 * c.x - q1 * c.y);
        ohi[j] = f2bfu(q1 * c.x + q0 * c.y);
        float k0 = bf2f(klo[j]), k1 = bf2f(khi[j]);
        plo[j] = f2bfu(k0 * c.x - k1 * c.y);
        phi[j] = f2bfu(k1 * c.x + k0 * c.y);
    }
    *(u16x8*)(Q + base + d0) = olo;
    *(u16x8*)(Q + base + 64 + d0) = ohi;
    *(u16x8*)(Kt + base + d0) = plo;
    *(u16x8*)(Kt + base + 64 + d0) = phi;
}

// ---------------- bf16 MFMA flash attention; O (bf16) overwrites Q panel
// 4 waves; wave owns 16 q-rows. KT=32. All fragment layouts identical to the
// GEMM kernel above (a/b: row=lane&15, kchunk=lane>>4; C/D: col=lane&15,
// row=(lane>>4)*4+reg).
#define AQT 64
#define AKT 32

__global__ __launch_bounds__(256, 2)
void attn_mfma_kernel(unsigned short* __restrict__ Q,
                      const unsigned short* __restrict__ Kp,
                      const unsigned short* __restrict__ Vp) {
    __shared__ unsigned short Ks[AKT * DK];   // 8 KB, XOR-swizzled rows
    __shared__ float Vt[DK][AKT + 4];         // 18 KB, V transposed [d][kk]
    __shared__ float Ps[AQT][AKT + 1];        // 8.25 KB, per-wave rows
    const int tid = threadIdx.x;
    const int lane = tid & 63, wid = tid >> 6;
    const int lrow = lane & 15, lkc = lane >> 4;
    const int bh = blockIdx.y;
    const int q0 = blockIdx.x * AQT;
    unsigned short* qpanel = Q + (size_t)bh * SEQ * DK;
    const unsigned short* kpanel = Kp + (size_t)bh * SEQ * DK;
    const unsigned short* vpanel = Vp + (size_t)bh * SEQ * DK;
    const float scale = 0.08838834764831845f;   // 1/sqrt(128)

    // Q fragments: 4 k-chunks of 32, held in registers for the whole kernel
    bf16x8 qfrag[4];
    {
        const unsigned short* qsrc = qpanel + (size_t)(q0 + wid * 16 + lrow) * DK + lkc * 8;
        #pragma unroll
        for (int c = 0; c < 4; ++c)
            qfrag[c] = *(const bf16x8*)(qsrc + c * 32);
    }

    float m_i[4], l_i[4];
    f32x4 oacc[8];
    #pragma unroll
    for (int r = 0; r < 4; ++r) { m_i[r] = -1e30f; l_i[r] = 0.f; }
    #pragma unroll
    for (int dt = 0; dt < 8; ++dt) oacc[dt] = (f32x4){0.f, 0.f, 0.f, 0.f};

    for (int kv0 = 0; kv0 < SEQ; kv0 += AKT) {
        __syncthreads();                       // prior reads of Ks/Vt done
        // ---- stage K tile, bf16, swizzled (elem ^= (row&7)<<3; 8-elem units)
        {
            int krow = tid >> 3, d0 = (tid & 7) * 16;
            const unsigned short* src = kpanel + (size_t)(kv0 + krow) * DK + d0;
            u16x8 v0 = *(const u16x8*)src;
            u16x8 v1 = *(const u16x8*)(src + 8);
            int sw = (krow & 7) << 3;
            *(u16x8*)&Ks[(krow * DK + d0) ^ sw]     = v0;
            *(u16x8*)&Ks[(krow * DK + d0 + 8) ^ sw] = v1;
        }
        // ---- stage V tile transposed to f32: Vt[d][kk]
        {
            int kk = tid & 31, dgrp = tid >> 5;
            const unsigned short* src = vpanel + (size_t)(kv0 + kk) * DK + dgrp * 16;
            u16x8 v0 = *(const u16x8*)src;
            u16x8 v1 = *(const u16x8*)(src + 8);
            #pragma unroll
            for (int j = 0; j < 8; ++j) {
                Vt[dgrp * 16 + j][kk]     = bf2f(v0[j]);
                Vt[dgrp * 16 + 8 + j][kk] = bf2f(v1[j]);
            }
        }
        __syncthreads();

        // ---- QK^T: S[q][k], q=(lane>>4)*4+r, k=lane&15 (+16*t)
        f32x4 sacc[2];
        sacc[0] = (f32x4){0.f, 0.f, 0.f, 0.f};
        sacc[1] = (f32x4){0.f, 0.f, 0.f, 0.f};
        #pragma unroll
        for (int t = 0; t < 2; ++t) {
            int krl = t * 16 + lrow;
            int sw = (krl & 7) << 3;
            #pragma unroll
            for (int c = 0; c < 4; ++c) {
                bf16x8 kf = *(const bf16x8*)&Ks[(krl * DK + c * 32 + lkc * 8) ^ sw];
                sacc[t] = __builtin_amdgcn_mfma_f32_16x16x32_bf16(qfrag[c], kf, sacc[t], 0, 0, 0);
            }
        }

        // ---- online softmax (row = 16 lanes sharing lane>>4; shfl_xor 1..8)
        #pragma unroll
        for (int r = 0; r < 4; ++r) {
            float s0 = sacc[0][r] * scale;
            float s1 = sacc[1][r] * scale;
            float mx = fmaxf(s0, s1);
            #pragma unroll
            for (int off = 1; off <= 8; off <<= 1)
                mx = fmaxf(mx, __shfl_xor(mx, off, 64));
            float mnew = fmaxf(m_i[r], mx);
            float corr = __expf(m_i[r] - mnew);
            float p0 = __expf(s0 - mnew);
            float p1 = __expf(s1 - mnew);
            float rs = p0 + p1;
            #pragma unroll
            for (int off = 1; off <= 8; off <<= 1)
                rs += __shfl_xor(rs, off, 64);
            l_i[r] = l_i[r] * corr + rs;
            m_i[r] = mnew;
            #pragma unroll
            for (int dt = 0; dt < 8; ++dt) oacc[dt][r] *= corr;
            int prow = wid * 16 + lkc * 4 + r;     // wave-private rows
            Ps[prow][lrow]      = p0;
            Ps[prow][16 + lrow] = p1;
        }

        // ---- P a-frag from per-wave LDS (same-wave dep; compiler waits lgkm)
        bf16x8 pfrag;
        {
            int arow = wid * 16 + lrow;
            #pragma unroll
            for (int j = 0; j < 8; ++j)
                pfrag[j] = (short)f2bfu(Ps[arow][lkc * 8 + j]);
        }

        // ---- PV: O[q][d] += P * V  (b-frag row = d, elements Vt[d][k])
        #pragma unroll
        for (int dt = 0; dt < 8; ++dt) {
            int d = dt * 16 + lrow;
            bf16x8 vf;
            #pragma unroll
            for (int j = 0; j < 8; ++j)
                vf[j] = (short)f2bfu(Vt[d][lkc * 8 + j]);
            oacc[dt] = __builtin_amdgcn_mfma_f32_16x16x32_bf16(pfrag, vf, oacc[dt], 0, 0, 0);
        }
    }

    // ---- normalize + write O (bf16) over own Q rows
    float inv[4];
    #pragma unroll
    for (int r = 0; r < 4; ++r) inv[r] = 1.0f / l_i[r];
    #pragma unroll
    for (int dt = 0; dt < 8; ++dt) {
        #pragma unroll
        for (int r = 0; r < 4; ++r) {
            int q = q0 + wid * 16 + lkc * 4 + r;
            qpanel[(size_t)q * DK + dt * 16 + lrow] = f2bfu(oacc[dt][r] * inv[r]);
        }
    }
}

// ---------------------------------------------------------------------------
extern "C" void kernel_launch(void* const* d_in, const int* in_sizes, int n_in,
                              void* d_out, int out_size, void* d_ws, size_t ws_size,
                              hipStream_t stream) {
    const float* x   = (const float*)d_in[0];
    const float* w_q = (const float*)d_in[1];
    const float* b_q = (const float*)d_in[2];
    const float* w_k = (const float*)d_in[3];
    const float* b_k = (const float*)d_in[4];
    const float* w_v = (const float*)d_in[5];
    const float* b_v = (const float*)d_in[6];
    const float* w_o = (const float*)d_in[7];
    const float* b_o = (const float*)d_in[8];
    float* out = (float*)d_out;

    char* ws = (char*)d_ws;
    const size_t bfTensor = (size_t)BATCH * NHEADS * SEQ * DK * 2;   // 16,777,216 B
    unsigned short* Qbf = (unsigned short*)(ws);
    unsigned short* Kbf = (unsigned short*)(ws + bfTensor);
    unsigned short* Vbf = (unsigned short*)(ws + 2 * bfTensor);
    unsigned short* Xbf = (unsigned short*)(ws + 3 * bfTensor);
    unsigned short* Wbf = (unsigned short*)(ws + 4 * bfTensor);      // 4 weights
    float2*         cs  = (float2*)(ws + 6 * bfTensor);              // 1 MB
    // total = 6*16.78MB + 1MB = 101,711,872 B

    rope_table_kernel<<<(SEQ * 64 + 255) / 256, 256, 0, stream>>>(cs);
    convert_kernel<<<(XN + 4 * WN) / 4 / 256, 256, 0, stream>>>(x, w_q, w_k, w_v, w_o, Xbf, Wbf);

    dim3 ggrid(MTOT / BM, D_MODEL / BN);
    gemm_bf16_kernel<0, 1><<<ggrid, 256, 0, stream>>>(Xbf, Wbf + 0 * (size_t)WN, b_q, Qbf);
    gemm_bf16_kernel<0, 1><<<ggrid, 256, 0, stream>>>(Xbf, Wbf + 1 * (size_t)WN, b_k, Kbf);
    gemm_bf16_kernel<0, 1><<<ggrid, 256, 0, stream>>>(Xbf, Wbf + 2 * (size_t)WN, b_v, Vbf);

    rope_kernel<<<(BATCH * NHEADS * SEQ * 8 + 255) / 256, 256, 0, stream>>>(Qbf, Kbf, cs);

    attn_mfma_kernel<<<dim3(SEQ / AQT, BATCH * NHEADS), 256, 0, stream>>>(Qbf, Kbf, Vbf);

    gemm_bf16_kernel<1, 0><<<ggrid, 256, 0, stream>>>(Qbf, Wbf + 3 * (size_t)WN, b_o, out);
}

// Round 6
// 539.471 us; speedup vs baseline: 5.4575x; 1.3387x over previous
//
#include <hip/hip_runtime.h>
#include <hip/hip_bf16.h>
#include <math.h>

// ---------------------------------------------------------------------------
// Round 6: attention LDS-conflict fix. bf16 Vs[d][72]/Ps[q][72] layouts
// (conflict-free b128 fragment reads), KT=64, defer-max (THR=8), K staged via
// global_load_lds with pre-swizzled source, 1/sqrt(d) folded into RoPE.
// GEMMs unchanged (m97 structure).
// ws: Qbf | Kbf | Vbf | Xbf | Wbf(4) | cs  == 101,711,872 B
// ---------------------------------------------------------------------------

#define D_MODEL 2048
#define NHEADS  16
#define DK      128
#define BATCH   2
#define SEQ     2048
#define MTOT    (BATCH*SEQ)            // 4096
#define XN      (MTOT*D_MODEL)         // 8,388,608
#define WN      (D_MODEL*D_MODEL)      // 4,194,304

typedef __attribute__((ext_vector_type(8))) short bf16x8;
typedef __attribute__((ext_vector_type(4))) float f32x4;
typedef __attribute__((ext_vector_type(8))) unsigned short u16x8;

__device__ __forceinline__ float bf2f(unsigned short u) {
    union { unsigned int i; float f; } v; v.i = ((unsigned int)u) << 16; return v.f;
}
__device__ __forceinline__ unsigned short f2bfu(float f) {
    __hip_bfloat16 h = __float2bfloat16(f);   // RNE
    return *reinterpret_cast<unsigned short*>(&h);
}
__device__ __forceinline__ void async_copy16(const unsigned short* g, unsigned short* l) {
    __builtin_amdgcn_global_load_lds((const __attribute__((address_space(1))) void*)g,
                                     (__attribute__((address_space(3))) void*)l, 16, 0, 0);
}

// ---------------- RoPE cos/sin table
__global__ void rope_table_kernel(float2* __restrict__ cs) {
    int idx = blockIdx.x * blockDim.x + threadIdx.x;
    if (idx >= SEQ * 64) return;
    int s = idx >> 6, j = idx & 63;
    double inv = pow(10000.0, -(double)j / 64.0);
    double f = (double)s * inv;
    cs[idx] = make_float2((float)cos(f), (float)sin(f));
}

// ---------------- fp32 -> bf16 conversion of x and the 4 weights
__global__ void convert_kernel(const float* __restrict__ x,
                               const float* __restrict__ wq, const float* __restrict__ wk,
                               const float* __restrict__ wv, const float* __restrict__ wo,
                               unsigned short* __restrict__ Xbf, unsigned short* __restrict__ Wbf) {
    size_t e = ((size_t)blockIdx.x * blockDim.x + threadIdx.x) * 4;
    const float* src; unsigned short* dst;
    if (e < XN) { src = x + e; dst = Xbf + e; }
    else {
        size_t r = e - XN; int w = (int)(r >> 22); size_t o = r & (WN - 1);
        src = (w == 0 ? wq : w == 1 ? wk : w == 2 ? wv : wo) + o;
        dst = Wbf + (size_t)w * WN + o;
    }
    float4 v = *(const float4*)src;
    ushort4 u;
    u.x = f2bfu(v.x); u.y = f2bfu(v.y); u.z = f2bfu(v.z); u.w = f2bfu(v.w);
    *(ushort4*)dst = u;
}

// ---------------- bf16 MFMA GEMM: C[M=4096][N=2048] = A*W^T + bias, K=2048
#define BM 128
#define BN 128
#define BK 32

template<int AMODE, int CMODE>
__global__ __launch_bounds__(256, 2)
void gemm_bf16_kernel(const unsigned short* __restrict__ A,
                      const unsigned short* __restrict__ W,
                      const float* __restrict__ bias, void* __restrict__ Cout) {
    __shared__ unsigned short smem[8192];   // As[128][32] | Bs[128][32]
    const int tid = threadIdx.x;
    const int lane = tid & 63, wid = tid >> 6;
    const int wm = wid >> 1, wn = wid & 1;
    const int m0 = blockIdx.x * BM, n0 = blockIdx.y * BN;

    f32x4 acc[4][4];
    #pragma unroll
    for (int i = 0; i < 4; ++i)
        #pragma unroll
        for (int j = 0; j < 4; ++j) acc[i][j] = (f32x4){0.f, 0.f, 0.f, 0.f};

    const int lrow = lane & 15, lkc = lane >> 4;

    for (int k0 = 0; k0 < D_MODEL; k0 += BK) {
        #pragma unroll
        for (int i = 0; i < 4; ++i) {
            const int off = i * 4096 + wid * 1024 + lane * 16;   // byte in 16KB tile-pair
            const unsigned short* src;
            if (i < 2) {                          // A region [0,8192)
                int elem = off >> 1, row = elem >> 5, col = elem & 31;
                if (AMODE == 0) {
                    src = A + (size_t)(m0 + row) * D_MODEL + k0 + col;
                } else {
                    int m = m0 + row, b = m >> 11, s = m & 2047;
                    src = A + (((size_t)(b * NHEADS + (k0 >> 7))) * SEQ + s) * DK + (k0 & 127) + col;
                }
            } else {                              // B region
                int elem = (off - 8192) >> 1, row = elem >> 5, col = elem & 31;
                src = W + (size_t)(n0 + row) * D_MODEL + k0 + col;
            }
            async_copy16(src, &smem[(i * 4096 + wid * 1024) >> 1]);  // wave-uniform dest
        }
        __syncthreads();

        bf16x8 a[4], b[4];
        #pragma unroll
        for (int mi = 0; mi < 4; ++mi)
            a[mi] = *(const bf16x8*)&smem[(wm * 64 + mi * 16 + lrow) * 32 + lkc * 8];
        #pragma unroll
        for (int ni = 0; ni < 4; ++ni)
            b[ni] = *(const bf16x8*)&smem[4096 + (wn * 64 + ni * 16 + lrow) * 32 + lkc * 8];
        #pragma unroll
        for (int mi = 0; mi < 4; ++mi)
            #pragma unroll
            for (int ni = 0; ni < 4; ++ni)
                acc[mi][ni] = __builtin_amdgcn_mfma_f32_16x16x32_bf16(a[mi], b[ni], acc[mi][ni], 0, 0, 0);
        __syncthreads();
    }

    // epilogue: C/D layout col=lane&15, row=(lane>>4)*4+r  [m89-verified]
    const int lq = lane >> 4;
    #pragma unroll
    for (int ni = 0; ni < 4; ++ni) {
        int col = n0 + wn * 64 + ni * 16 + lrow;
        float bv = bias[col];
        #pragma unroll
        for (int mi = 0; mi < 4; ++mi) {
            #pragma unroll
            for (int r = 0; r < 4; ++r) {
                int row = m0 + wm * 64 + mi * 16 + lq * 4 + r;
                float v = acc[mi][ni][r] + bv;
                if (CMODE == 0) {
                    ((float*)Cout)[(size_t)row * D_MODEL + col] = v;
                } else {
                    int bb = row >> 11, s = row & 2047, h = col >> 7, d = col & 127;
                    ((unsigned short*)Cout)[(((size_t)(bb * NHEADS + h)) * SEQ + s) * DK + d] = f2bfu(v);
                }
            }
        }
    }
}

// ---------------- in-place RoPE on bf16 Q and K; Q additionally scaled 1/sqrt(DK)
__global__ void rope_kernel(unsigned short* __restrict__ Q, unsigned short* __restrict__ Kt,
                            const float2* __restrict__ cs) {
    const float qscale = 0.08838834764831845f;   // 1/sqrt(128), folded into Q
    int idx = blockIdx.x * blockDim.x + threadIdx.x;   // B*H*S*8
    if (idx >= BATCH * NHEADS * SEQ * 8) return;
    int j8 = idx & 7, bhs = idx >> 3, s = bhs & (SEQ - 1);
    int d0 = j8 * 8;
    size_t base = (size_t)bhs * DK;
    u16x8 qlo = *(const u16x8*)(Q + base + d0);
    u16x8 qhi = *(const u16x8*)(Q + base + 64 + d0);
    u16x8 klo = *(const u16x8*)(Kt + base + d0);
    u16x8 khi = *(const u16x8*)(Kt + base + 64 + d0);
    u16x8 olo, ohi, plo, phi;
    #pragma unroll
    for (int j = 0; j < 8; ++j) {
        float2 c = cs[(s << 6) + d0 + j];
        float q0 = bf2f(qlo[j]), q1 = bf2f(qhi[j]);
        olo[j] = f2bfu((q0 * c.x - q1 * c.y) * qscale);
        ohi[j] = f2bfu((q1 * c.x + q0 * c.y) * qscale);
        float k0 = bf2f(klo[j]), k1 = bf2f(khi[j]);
        plo[j] = f2bfu(k0 * c.x - k1 * c.y);
        phi[j] = f2bfu(k1 * c.x + k0 * c.y);
    }
    *(u16x8*)(Q + base + d0) = olo;
    *(u16x8*)(Q + base + 64 + d0) = ohi;
    *(u16x8*)(Kt + base + d0) = plo;
    *(u16x8*)(Kt + base + 64 + d0) = phi;
}

// ---------------- bf16 MFMA flash attention; O (bf16) overwrites Q panel
// 4 waves x 16 q-rows; KT=64. Ks XOR-swizzled bf16 (async-staged, pre-swizzled
// source); Vs bf16 [d][stride 72] (conflict-free b128 reads); Ps bf16 [q][72].
#define AQT 64
#define AKT 64
#define VSS 72
#define PSS 72

__global__ __launch_bounds__(256, 3)
void attn_mfma_kernel(unsigned short* __restrict__ Q,
                      const unsigned short* __restrict__ Kp,
                      const unsigned short* __restrict__ Vp) {
    __shared__ unsigned short Ks[AKT * DK];     // 16384 B, XOR-swizzled rows
    __shared__ unsigned short Vs[DK * VSS];     // 18432 B, V^T [d][kk]
    __shared__ unsigned short Ps[AQT * PSS];    //  9216 B, P [q][kk], wave-private rows
    const int tid = threadIdx.x;
    const int lane = tid & 63, wid = tid >> 6;
    const int lrow = lane & 15, lkc = lane >> 4;
    const int bh = blockIdx.y;
    const int q0 = blockIdx.x * AQT;
    unsigned short* qpanel = Q + (size_t)bh * SEQ * DK;
    const unsigned short* kpanel = Kp + (size_t)bh * SEQ * DK;
    const unsigned short* vpanel = Vp + (size_t)bh * SEQ * DK;

    // Q fragments (pre-scaled by rope), held in registers all loop
    bf16x8 qfrag[4];
    {
        const unsigned short* qsrc = qpanel + (size_t)(q0 + wid * 16 + lrow) * DK + lkc * 8;
        #pragma unroll
        for (int c = 0; c < 4; ++c)
            qfrag[c] = *(const bf16x8*)(qsrc + c * 32);
    }

    float m_i[4], l_i[4];
    f32x4 oacc[8];
    #pragma unroll
    for (int r = 0; r < 4; ++r) { m_i[r] = -1e30f; l_i[r] = 0.f; }
    #pragma unroll
    for (int dt = 0; dt < 8; ++dt) oacc[dt] = (f32x4){0.f, 0.f, 0.f, 0.f};

    const int v_kk = lane;          // V staging: row kk = lane, d-block = wid*32
    const int v_d0 = wid * 32;

    for (int kv0 = 0; kv0 < SEQ; kv0 += AKT) {
        __syncthreads();                         // prior tile's Ks/Vs reads done
        // ---- K tile via global_load_lds: linear dest, pre-swizzled source
        #pragma unroll
        for (int i = 0; i < 4; ++i) {
            int dstByte = i * 4096 + wid * 1024 + lane * 16;
            int elem = dstByte >> 1;
            int row = elem >> 7, col = elem & 127;
            int colS = col ^ ((row & 7) << 3);
            async_copy16(kpanel + (size_t)(kv0 + row) * DK + colS,
                         &Ks[i * 2048 + wid * 512]);   // wave-uniform base
        }
        // ---- V tile -> Vs[d][kk] (bf16 transpose-scatter; 2 lanes/bank = free)
        {
            const unsigned short* src = vpanel + (size_t)(kv0 + v_kk) * DK + v_d0;
            u16x8 a0 = *(const u16x8*)(src);
            u16x8 a1 = *(const u16x8*)(src + 8);
            u16x8 a2 = *(const u16x8*)(src + 16);
            u16x8 a3 = *(const u16x8*)(src + 24);
            #pragma unroll
            for (int j = 0; j < 8; ++j) {
                Vs[(v_d0 + j)      * VSS + v_kk] = a0[j];
                Vs[(v_d0 + 8 + j)  * VSS + v_kk] = a1[j];
                Vs[(v_d0 + 16 + j) * VSS + v_kk] = a2[j];
                Vs[(v_d0 + 24 + j) * VSS + v_kk] = a3[j];
            }
        }
        __syncthreads();                         // drains vmcnt (K) + lgkm (V)

        // ---- QK^T: S[q=(lkc*4+r)][k=t*16+lrow], 16 MFMA
        f32x4 sacc[4];
        #pragma unroll
        for (int t = 0; t < 4; ++t) sacc[t] = (f32x4){0.f, 0.f, 0.f, 0.f};
        #pragma unroll
        for (int t = 0; t < 4; ++t) {
            int krl = t * 16 + lrow;
            int sw = (krl & 7) << 3;
            #pragma unroll
            for (int c = 0; c < 4; ++c) {
                bf16x8 kf = *(const bf16x8*)&Ks[(krl * DK + c * 32 + lkc * 8) ^ sw];
                sacc[t] = __builtin_amdgcn_mfma_f32_16x16x32_bf16(qfrag[c], kf, sacc[t], 0, 0, 0);
            }
        }

        // ---- row maxes (16-lane groups; lanes differing in bits 0..3)
        float mx[4];
        #pragma unroll
        for (int r = 0; r < 4; ++r) {
            float v = fmaxf(fmaxf(sacc[0][r], sacc[1][r]), fmaxf(sacc[2][r], sacc[3][r]));
            #pragma unroll
            for (int off = 1; off <= 8; off <<= 1)
                v = fmaxf(v, __shfl_xor(v, off, 64));
            mx[r] = v;
        }
        // ---- defer-max (T13, THR=8): rescale only when some row's max jumped
        int cond = (mx[0] - m_i[0] <= 8.f) && (mx[1] - m_i[1] <= 8.f) &&
                   (mx[2] - m_i[2] <= 8.f) && (mx[3] - m_i[3] <= 8.f);
        if (!__all(cond)) {
            #pragma unroll
            for (int r = 0; r < 4; ++r) {
                float mnew = fmaxf(m_i[r], mx[r]);
                float corr = __expf(m_i[r] - mnew);
                l_i[r] *= corr;
                #pragma unroll
                for (int dt = 0; dt < 8; ++dt) oacc[dt][r] *= corr;
                m_i[r] = mnew;
            }
        }
        // ---- P = exp(S - m), row-sum, write bf16 Ps
        #pragma unroll
        for (int r = 0; r < 4; ++r) {
            float p0 = __expf(sacc[0][r] - m_i[r]);
            float p1 = __expf(sacc[1][r] - m_i[r]);
            float p2 = __expf(sacc[2][r] - m_i[r]);
            float p3 = __expf(sacc[3][r] - m_i[r]);
            float rs = (p0 + p1) + (p2 + p3);
            #pragma unroll
            for (int off = 1; off <= 8; off <<= 1)
                rs += __shfl_xor(rs, off, 64);
            l_i[r] += rs;
            int pb = (wid * 16 + lkc * 4 + r) * PSS;
            Ps[pb + lrow]      = f2bfu(p0);
            Ps[pb + 16 + lrow] = f2bfu(p1);
            Ps[pb + 32 + lrow] = f2bfu(p2);
            Ps[pb + 48 + lrow] = f2bfu(p3);
        }

        // ---- PV: conflict-free b128 fragment reads, 16 MFMA
        const int arow = (wid * 16 + lrow) * PSS;
        bf16x8 pfA = *(const bf16x8*)&Ps[arow + lkc * 8];
        bf16x8 pfB = *(const bf16x8*)&Ps[arow + 32 + lkc * 8];
        #pragma unroll
        for (int dt = 0; dt < 8; ++dt) {
            int db = (dt * 16 + lrow) * VSS;
            bf16x8 vfA = *(const bf16x8*)&Vs[db + lkc * 8];
            bf16x8 vfB = *(const bf16x8*)&Vs[db + 32 + lkc * 8];
            oacc[dt] = __builtin_amdgcn_mfma_f32_16x16x32_bf16(pfA, vfA, oacc[dt], 0, 0, 0);
            oacc[dt] = __builtin_amdgcn_mfma_f32_16x16x32_bf16(pfB, vfB, oacc[dt], 0, 0, 0);
        }
    }

    // ---- normalize + write O (bf16) over own Q rows
    float inv[4];
    #pragma unroll
    for (int r = 0; r < 4; ++r) inv[r] = 1.0f / l_i[r];
    #pragma unroll
    for (int dt = 0; dt < 8; ++dt) {
        #pragma unroll
        for (int r = 0; r < 4; ++r) {
            int q = q0 + wid * 16 + lkc * 4 + r;
            qpanel[(size_t)q * DK + dt * 16 + lrow] = f2bfu(oacc[dt][r] * inv[r]);
        }
    }
}

// ---------------------------------------------------------------------------
extern "C" void kernel_launch(void* const* d_in, const int* in_sizes, int n_in,
                              void* d_out, int out_size, void* d_ws, size_t ws_size,
                              hipStream_t stream) {
    const float* x   = (const float*)d_in[0];
    const float* w_q = (const float*)d_in[1];
    const float* b_q = (const float*)d_in[2];
    const float* w_k = (const float*)d_in[3];
    const float* b_k = (const float*)d_in[4];
    const float* w_v = (const float*)d_in[5];
    const float* b_v = (const float*)d_in[6];
    const float* w_o = (const float*)d_in[7];
    const float* b_o = (const float*)d_in[8];
    float* out = (float*)d_out;

    char* ws = (char*)d_ws;
    const size_t bfTensor = (size_t)BATCH * NHEADS * SEQ * DK * 2;   // 16,777,216 B
    unsigned short* Qbf = (unsigned short*)(ws);
    unsigned short* Kbf = (unsigned short*)(ws + bfTensor);
    unsigned short* Vbf = (unsigned short*)(ws + 2 * bfTensor);
    unsigned short* Xbf = (unsigned short*)(ws + 3 * bfTensor);
    unsigned short* Wbf = (unsigned short*)(ws + 4 * bfTensor);      // 4 weights
    float2*         cs  = (float2*)(ws + 6 * bfTensor);              // 1 MB
    // total = 6*16.78MB + 1MB = 101,711,872 B

    rope_table_kernel<<<(SEQ * 64 + 255) / 256, 256, 0, stream>>>(cs);
    convert_kernel<<<(XN + 4 * WN) / 4 / 256, 256, 0, stream>>>(x, w_q, w_k, w_v, w_o, Xbf, Wbf);

    dim3 ggrid(MTOT / BM, D_MODEL / BN);
    gemm_bf16_kernel<0, 1><<<ggrid, 256, 0, stream>>>(Xbf, Wbf + 0 * (size_t)WN, b_q, Qbf);
    gemm_bf16_kernel<0, 1><<<ggrid, 256, 0, stream>>>(Xbf, Wbf + 1 * (size_t)WN, b_k, Kbf);
    gemm_bf16_kernel<0, 1><<<ggrid, 256, 0, stream>>>(Xbf, Wbf + 2 * (size_t)WN, b_v, Vbf);

    rope_kernel<<<(BATCH * NHEADS * SEQ * 8 + 255) / 256, 256, 0, stream>>>(Qbf, Kbf, cs);

    attn_mfma_kernel<<<dim3(SEQ / AQT, BATCH * NHEADS), 256, 0, stream>>>(Qbf, Kbf, Vbf);

    gemm_bf16_kernel<1, 0><<<ggrid, 256, 0, stream>>>(Qbf, Wbf + 3 * (size_t)WN, b_o, out);
}

// Round 11
// 508.463 us; speedup vs baseline: 5.7903x; 1.0610x over previous
//
#include <hip/hip_runtime.h>
#include <hip/hip_bf16.h>
#include <math.h>

// ---------------------------------------------------------------------------
// Round 11 (= round 7 kernel, fifth submission; rounds 7-10 died to infra):
// V-proj GEMM emits V^T (CMODE2, LDS-transposed epilogue); attention stages
// BOTH K and V via global_load_lds with pre-swizzled sources, double-buffered
// with raw s_barrier + counted vmcnt(8) 2-phase pipeline.
// GEMMs otherwise unchanged (m97 structure). RoPE folds 1/sqrt(dk) into Q.
// ws: Qbf | Kbf | VTbf | Xbf | Wbf(4) | cs  == 101,711,872 B
// ---------------------------------------------------------------------------

#define D_MODEL 2048
#define NHEADS  16
#define DK      128
#define BATCH   2
#define SEQ     2048
#define MTOT    (BATCH*SEQ)            // 4096
#define XN      (MTOT*D_MODEL)         // 8,388,608
#define WN      (D_MODEL*D_MODEL)      // 4,194,304

typedef __attribute__((ext_vector_type(8))) short bf16x8;
typedef __attribute__((ext_vector_type(4))) float f32x4;
typedef __attribute__((ext_vector_type(8))) unsigned short u16x8;

__device__ __forceinline__ float bf2f(unsigned short u) {
    union { unsigned int i; float f; } v; v.i = ((unsigned int)u) << 16; return v.f;
}
__device__ __forceinline__ unsigned short f2bfu(float f) {
    __hip_bfloat16 h = __float2bfloat16(f);   // RNE
    return *reinterpret_cast<unsigned short*>(&h);
}
__device__ __forceinline__ void async_copy16(const unsigned short* g, unsigned short* l) {
    __builtin_amdgcn_global_load_lds((const __attribute__((address_space(1))) void*)g,
                                     (__attribute__((address_space(3))) void*)l, 16, 0, 0);
}

// ---------------- RoPE cos/sin table
__global__ void rope_table_kernel(float2* __restrict__ cs) {
    int idx = blockIdx.x * blockDim.x + threadIdx.x;
    if (idx >= SEQ * 64) return;
    int s = idx >> 6, j = idx & 63;
    double inv = pow(10000.0, -(double)j / 64.0);
    double f = (double)s * inv;
    cs[idx] = make_float2((float)cos(f), (float)sin(f));
}

// ---------------- fp32 -> bf16 conversion of x and the 4 weights
__global__ void convert_kernel(const float* __restrict__ x,
                               const float* __restrict__ wq, const float* __restrict__ wk,
                               const float* __restrict__ wv, const float* __restrict__ wo,
                               unsigned short* __restrict__ Xbf, unsigned short* __restrict__ Wbf) {
    size_t e = ((size_t)blockIdx.x * blockDim.x + threadIdx.x) * 4;
    const float* src; unsigned short* dst;
    if (e < XN) { src = x + e; dst = Xbf + e; }
    else {
        size_t r = e - XN; int w = (int)(r >> 22); size_t o = r & (WN - 1);
        src = (w == 0 ? wq : w == 1 ? wk : w == 2 ? wv : wo) + o;
        dst = Wbf + (size_t)w * WN + o;
    }
    float4 v = *(const float4*)src;
    ushort4 u;
    u.x = f2bfu(v.x); u.y = f2bfu(v.y); u.z = f2bfu(v.z); u.w = f2bfu(v.w);
    *(ushort4*)dst = u;
}

// ---------------- bf16 MFMA GEMM: C[M=4096][N=2048] = A*W^T + bias, K=2048
// AMODE 0: A row-major bf16.  AMODE 1: A head-major bf16 [B][H][S][DK].
// CMODE 0: C fp32 row-major.  CMODE 1: C bf16 head-major [B][H][S][DK].
// CMODE 2: C bf16 head-major TRANSPOSED [B][H][DK][S]  (for V^T).
#define BM 128
#define BN 128
#define BK 32

template<int AMODE, int CMODE>
__global__ __launch_bounds__(256, 2)
void gemm_bf16_kernel(const unsigned short* __restrict__ A,
                      const unsigned short* __restrict__ W,
                      const float* __restrict__ bias, void* __restrict__ Cout) {
    __shared__ unsigned short smem[8704];   // K-loop: As[128][32]|Bs[128][32]; CMODE2 epilogue: [128][68]
    const int tid = threadIdx.x;
    const int lane = tid & 63, wid = tid >> 6;
    const int wm = wid >> 1, wn = wid & 1;
    const int m0 = blockIdx.x * BM, n0 = blockIdx.y * BN;

    f32x4 acc[4][4];
    #pragma unroll
    for (int i = 0; i < 4; ++i)
        #pragma unroll
        for (int j = 0; j < 4; ++j) acc[i][j] = (f32x4){0.f, 0.f, 0.f, 0.f};

    const int lrow = lane & 15, lkc = lane >> 4;

    for (int k0 = 0; k0 < D_MODEL; k0 += BK) {
        #pragma unroll
        for (int i = 0; i < 4; ++i) {
            const int off = i * 4096 + wid * 1024 + lane * 16;   // byte in 16KB tile-pair
            const unsigned short* src;
            if (i < 2) {                          // A region [0,8192)
                int elem = off >> 1, row = elem >> 5, col = elem & 31;
                if (AMODE == 0) {
                    src = A + (size_t)(m0 + row) * D_MODEL + k0 + col;
                } else {
                    int m = m0 + row, b = m >> 11, s = m & 2047;
                    src = A + (((size_t)(b * NHEADS + (k0 >> 7))) * SEQ + s) * DK + (k0 & 127) + col;
                }
            } else {                              // B region
                int elem = (off - 8192) >> 1, row = elem >> 5, col = elem & 31;
                src = W + (size_t)(n0 + row) * D_MODEL + k0 + col;
            }
            async_copy16(src, &smem[(i * 4096 + wid * 1024) >> 1]);  // wave-uniform dest
        }
        __syncthreads();

        bf16x8 a[4], b[4];
        #pragma unroll
        for (int mi = 0; mi < 4; ++mi)
            a[mi] = *(const bf16x8*)&smem[(wm * 64 + mi * 16 + lrow) * 32 + lkc * 8];
        #pragma unroll
        for (int ni = 0; ni < 4; ++ni)
            b[ni] = *(const bf16x8*)&smem[4096 + (wn * 64 + ni * 16 + lrow) * 32 + lkc * 8];
        #pragma unroll
        for (int mi = 0; mi < 4; ++mi)
            #pragma unroll
            for (int ni = 0; ni < 4; ++ni)
                acc[mi][ni] = __builtin_amdgcn_mfma_f32_16x16x32_bf16(a[mi], b[ni], acc[mi][ni], 0, 0, 0);
        __syncthreads();
    }

    // epilogue: C/D layout col=lane&15, row=(lane>>4)*4+r  [m89-verified]
    const int lq = lane >> 4;
    if (CMODE != 2) {
        #pragma unroll
        for (int ni = 0; ni < 4; ++ni) {
            int col = n0 + wn * 64 + ni * 16 + lrow;
            float bv = bias[col];
            #pragma unroll
            for (int mi = 0; mi < 4; ++mi) {
                #pragma unroll
                for (int r = 0; r < 4; ++r) {
                    int row = m0 + wm * 64 + mi * 16 + lq * 4 + r;
                    float v = acc[mi][ni][r] + bv;
                    if (CMODE == 0) {
                        ((float*)Cout)[(size_t)row * D_MODEL + col] = v;
                    } else {
                        int bb = row >> 11, s = row & 2047, h = col >> 7, d = col & 127;
                        ((unsigned short*)Cout)[(((size_t)(bb * NHEADS + h)) * SEQ + s) * DK + d] = f2bfu(v);
                    }
                }
            }
        }
    } else {
        // CMODE 2: write C^T head-major: VT[b][h][d][s].  BN==128==DK, so
        // h = n0>>7 and d = local col.  LDS-transpose in two 64-col halves.
        const int b = m0 >> 11;
        const int h = n0 >> 7;
        const int sbase = m0 & 2047;
        unsigned short* vtbase = (unsigned short*)Cout +
            (((size_t)(b * NHEADS + h)) * DK) * SEQ + sbase;
        #pragma unroll
        for (int half = 0; half < 2; ++half) {
            __syncthreads();
            if (wn == half) {
                #pragma unroll
                for (int ni = 0; ni < 4; ++ni) {
                    float bv = bias[n0 + half * 64 + ni * 16 + lrow];
                    #pragma unroll
                    for (int mi = 0; mi < 4; ++mi)
                        #pragma unroll
                        for (int r = 0; r < 4; ++r) {
                            int row = wm * 64 + mi * 16 + lq * 4 + r;
                            smem[row * 68 + ni * 16 + lrow] = f2bfu(acc[mi][ni][r] + bv);
                        }
                }
            }
            __syncthreads();
            // read transposed: thread -> d = half*64 + (tid>>2), s-chunk (tid&3)*32
            int dl = tid >> 2, s0 = (tid & 3) * 32;
            u16x8 o[4];
            #pragma unroll
            for (int j8 = 0; j8 < 4; ++j8)
                #pragma unroll
                for (int j = 0; j < 8; ++j)
                    o[j8][j] = smem[(s0 + j8 * 8 + j) * 68 + dl];
            unsigned short* dst = vtbase + (size_t)(half * 64 + dl) * SEQ + s0;
            #pragma unroll
            for (int j8 = 0; j8 < 4; ++j8)
                *(u16x8*)(dst + j8 * 8) = o[j8];
        }
    }
}

// ---------------- in-place RoPE on bf16 Q and K; Q additionally scaled 1/sqrt(DK)
__global__ void rope_kernel(unsigned short* __restrict__ Q, unsigned short* __restrict__ Kt,
                            const float2* __restrict__ cs) {
    const float qscale = 0.08838834764831845f;   // 1/sqrt(128), folded into Q
    int idx = blockIdx.x * blockDim.x + threadIdx.x;   // B*H*S*8
    if (idx >= BATCH * NHEADS * SEQ * 8) return;
    int j8 = idx & 7, bhs = idx >> 3, s = bhs & (SEQ - 1);
    int d0 = j8 * 8;
    size_t base = (size_t)bhs * DK;
    u16x8 qlo = *(const u16x8*)(Q + base + d0);
    u16x8 qhi = *(const u16x8*)(Q + base + 64 + d0);
    u16x8 klo = *(const u16x8*)(Kt + base + d0);
    u16x8 khi = *(const u16x8*)(Kt + base + 64 + d0);
    u16x8 olo, ohi, plo, phi;
    #pragma unroll
    for (int j = 0; j < 8; ++j) {
        float2 c = cs[(s << 6) + d0 + j];
        float q0 = bf2f(qlo[j]), q1 = bf2f(qhi[j]);
        olo[j] = f2bfu((q0 * c.x - q1 * c.y) * qscale);
        ohi[j] = f2bfu((q1 * c.x + q0 * c.y) * qscale);
        float k0 = bf2f(klo[j]), k1 = bf2f(khi[j]);
        plo[j] = f2bfu(k0 * c.x - k1 * c.y);
        phi[j] = f2bfu(k1 * c.x + k0 * c.y);
    }
    *(u16x8*)(Q + base + d0) = olo;
    *(u16x8*)(Q + base + 64 + d0) = ohi;
    *(u16x8*)(Kt + base + d0) = plo;
    *(u16x8*)(Kt + base + 64 + d0) = phi;
}

// ---------------- bf16 MFMA flash attention; O (bf16) overwrites Q panel
// 4 waves x 16 q-rows; KT=64; K and V^T both staged via global_load_lds with
// pre-swizzled source (16B-chunk XOR), double-buffered; raw-barrier 2-phase
// pipeline with counted vmcnt (8 loads/wave stay in flight across barriers).
#define AQT 64
#define AKT 64
#define NT  (SEQ/AKT)
#define PSS 72

__global__ __launch_bounds__(256, 2)
void attn_mfma_kernel(unsigned short* __restrict__ Q,
                      const unsigned short* __restrict__ Kp,
                      const unsigned short* __restrict__ VTp) {
    __shared__ unsigned short Ks[2][AKT * DK];   // 2 x 16 KB, row-swizzled
    __shared__ unsigned short Vs[2][DK * AKT];   // 2 x 16 KB, [d][kk] chunk-swizzled
    __shared__ unsigned short Ps[AQT * PSS];     // 9216 B, wave-private rows
    const int tid = threadIdx.x;
    const int lane = tid & 63, wid = tid >> 6;
    const int lrow = lane & 15, lkc = lane >> 4;
    const int bh = blockIdx.y;
    const int q0 = blockIdx.x * AQT;
    unsigned short* qpanel = Q + (size_t)bh * SEQ * DK;
    const unsigned short* kpanel  = Kp  + (size_t)bh * SEQ * DK;
    const unsigned short* vtpanel = VTp + (size_t)bh * DK * SEQ;

    // Q fragments (pre-scaled in rope), registers all loop
    bf16x8 qfrag[4];
    {
        const unsigned short* qsrc = qpanel + (size_t)(q0 + wid * 16 + lrow) * DK + lkc * 8;
        #pragma unroll
        for (int c = 0; c < 4; ++c)
            qfrag[c] = *(const bf16x8*)(qsrc + c * 32);
    }

    // staging: 8 global_load_lds per wave per tile (4 K + 4 V)
    const int st_elem = wid * 512 + lane * 8;          // per-thread first elem (of 8192)
    const int k_row = st_elem >> 7;                    // K: row 0..63 (per i: +16)
    const int k_colS = ((st_elem & 127)) ;             // col chunk base (lane*8 & 127)
    const int v_d = st_elem >> 6;                      // V: d 0..127 (per i: +32)
    const int v_c = (st_elem >> 3) & 7;                // chunk 0..7

#define STAGE(tt, bb)                                                                   \
    {                                                                                   \
        int kv0 = (tt) * AKT;                                                           \
        _Pragma("unroll")                                                               \
        for (int i = 0; i < 4; ++i) {                                                   \
            int row = i * 16 + k_row;                                                   \
            int colS = k_colS ^ ((row & 7) << 3);                                       \
            async_copy16(kpanel + (size_t)(kv0 + row) * DK + colS,                      \
                         &Ks[bb][i * 2048 + wid * 512]);                                \
        }                                                                               \
        _Pragma("unroll")                                                               \
        for (int i = 0; i < 4; ++i) {                                                   \
            int d = i * 32 + v_d;                                                       \
            int cS = v_c ^ (d & 7);                                                     \
            async_copy16(vtpanel + (size_t)d * SEQ + kv0 + cS * 8,                      \
                         &Vs[bb][i * 2048 + wid * 512]);                                \
        }                                                                               \
    }

    float m_i[4], l_i[4];
    f32x4 oacc[8];
    #pragma unroll
    for (int r = 0; r < 4; ++r) { m_i[r] = -1e30f; l_i[r] = 0.f; }
    #pragma unroll
    for (int dt = 0; dt < 8; ++dt) oacc[dt] = (f32x4){0.f, 0.f, 0.f, 0.f};

    STAGE(0, 0);
    int buf = 0;

    for (int tt = 0; tt < NT; ++tt) {
        if (tt + 1 < NT) {
            STAGE(tt + 1, buf ^ 1);
            asm volatile("s_waitcnt vmcnt(8)" ::: "memory");   // tile tt's 8 loads done
        } else {
            asm volatile("s_waitcnt vmcnt(0)" ::: "memory");
        }
        __builtin_amdgcn_sched_barrier(0);
        __builtin_amdgcn_s_barrier();                          // tile tt visible to all

        const unsigned short* KsB = Ks[buf];
        const unsigned short* VsB = Vs[buf];

        // ---- QK^T: S[q=(lkc*4+r)][k=t*16+lrow], 16 MFMA
        f32x4 sacc[4];
        #pragma unroll
        for (int t = 0; t < 4; ++t) sacc[t] = (f32x4){0.f, 0.f, 0.f, 0.f};
        #pragma unroll
        for (int t = 0; t < 4; ++t) {
            int krl = t * 16 + lrow;
            int sw = (krl & 7) << 3;
            #pragma unroll
            for (int c = 0; c < 4; ++c) {
                bf16x8 kf = *(const bf16x8*)&KsB[(krl * DK + c * 32 + lkc * 8) ^ sw];
                sacc[t] = __builtin_amdgcn_mfma_f32_16x16x32_bf16(qfrag[c], kf, sacc[t], 0, 0, 0);
            }
        }

        // ---- row maxes
        float mx[4];
        #pragma unroll
        for (int r = 0; r < 4; ++r) {
            float v = fmaxf(fmaxf(sacc[0][r], sacc[1][r]), fmaxf(sacc[2][r], sacc[3][r]));
            #pragma unroll
            for (int off = 1; off <= 8; off <<= 1)
                v = fmaxf(v, __shfl_xor(v, off, 64));
            mx[r] = v;
        }
        // ---- defer-max (T13, THR=8)
        int cond = (mx[0] - m_i[0] <= 8.f) && (mx[1] - m_i[1] <= 8.f) &&
                   (mx[2] - m_i[2] <= 8.f) && (mx[3] - m_i[3] <= 8.f);
        if (!__all(cond)) {
            #pragma unroll
            for (int r = 0; r < 4; ++r) {
                float mnew = fmaxf(m_i[r], mx[r]);
                float corr = __expf(m_i[r] - mnew);
                l_i[r] *= corr;
                #pragma unroll
                for (int dt = 0; dt < 8; ++dt) oacc[dt][r] *= corr;
                m_i[r] = mnew;
            }
        }
        // ---- P = exp(S-m), row-sum, bf16 Ps (wave-private rows)
        #pragma unroll
        for (int r = 0; r < 4; ++r) {
            float p0 = __expf(sacc[0][r] - m_i[r]);
            float p1 = __expf(sacc[1][r] - m_i[r]);
            float p2 = __expf(sacc[2][r] - m_i[r]);
            float p3 = __expf(sacc[3][r] - m_i[r]);
            float rs = (p0 + p1) + (p2 + p3);
            #pragma unroll
            for (int off = 1; off <= 8; off <<= 1)
                rs += __shfl_xor(rs, off, 64);
            l_i[r] += rs;
            int pb = (wid * 16 + lkc * 4 + r) * PSS;
            Ps[pb + lrow]      = f2bfu(p0);
            Ps[pb + 16 + lrow] = f2bfu(p1);
            Ps[pb + 32 + lrow] = f2bfu(p2);
            Ps[pb + 48 + lrow] = f2bfu(p3);
        }

        // ---- PV: chunk-swizzled b128 V^T reads (8 lanes x 8 positions = optimal)
        const int arow = (wid * 16 + lrow) * PSS;
        bf16x8 pfA = *(const bf16x8*)&Ps[arow + lkc * 8];
        bf16x8 pfB = *(const bf16x8*)&Ps[arow + 32 + lkc * 8];
        #pragma unroll
        for (int dt = 0; dt < 8; ++dt) {
            int d = dt * 16 + lrow;
            int basev = d * 64;
            bf16x8 vfA = *(const bf16x8*)&VsB[basev + ((lkc     ^ (lrow & 7)) * 8)];
            bf16x8 vfB = *(const bf16x8*)&VsB[basev + (((lkc+4) ^ (lrow & 7)) * 8)];
            oacc[dt] = __builtin_amdgcn_mfma_f32_16x16x32_bf16(pfA, vfA, oacc[dt], 0, 0, 0);
            oacc[dt] = __builtin_amdgcn_mfma_f32_16x16x32_bf16(pfB, vfB, oacc[dt], 0, 0, 0);
        }

        asm volatile("s_waitcnt lgkmcnt(0)" ::: "memory");     // LDS reads drained
        __builtin_amdgcn_sched_barrier(0);
        __builtin_amdgcn_s_barrier();                          // safe to overwrite buf^1
        buf ^= 1;
    }
#undef STAGE

    // ---- normalize + write O (bf16) over own Q rows
    float inv[4];
    #pragma unroll
    for (int r = 0; r < 4; ++r) inv[r] = 1.0f / l_i[r];
    #pragma unroll
    for (int dt = 0; dt < 8; ++dt) {
        #pragma unroll
        for (int r = 0; r < 4; ++r) {
            int q = q0 + wid * 16 + lkc * 4 + r;
            qpanel[(size_t)q * DK + dt * 16 + lrow] = f2bfu(oacc[dt][r] * inv[r]);
        }
    }
}

// ---------------------------------------------------------------------------
extern "C" void kernel_launch(void* const* d_in, const int* in_sizes, int n_in,
                              void* d_out, int out_size, void* d_ws, size_t ws_size,
                              hipStream_t stream) {
    const float* x   = (const float*)d_in[0];
    const float* w_q = (const float*)d_in[1];
    const float* b_q = (const float*)d_in[2];
    const float* w_k = (const float*)d_in[3];
    const float* b_k = (const float*)d_in[4];
    const float* w_v = (const float*)d_in[5];
    const float* b_v = (const float*)d_in[6];
    const float* w_o = (const float*)d_in[7];
    const float* b_o = (const float*)d_in[8];
    float* out = (float*)d_out;

    char* ws = (char*)d_ws;
    const size_t bfTensor = (size_t)BATCH * NHEADS * SEQ * DK * 2;   // 16,777,216 B
    unsigned short* Qbf  = (unsigned short*)(ws);
    unsigned short* Kbf  = (unsigned short*)(ws + bfTensor);
    unsigned short* VTbf = (unsigned short*)(ws + 2 * bfTensor);     // [b][h][d][s]
    unsigned short* Xbf  = (unsigned short*)(ws + 3 * bfTensor);
    unsigned short* Wbf  = (unsigned short*)(ws + 4 * bfTensor);     // 4 weights
    float2*         cs   = (float2*)(ws + 6 * bfTensor);             // 1 MB
    // total = 6*16.78MB + 1MB = 101,711,872 B

    rope_table_kernel<<<(SEQ * 64 + 255) / 256, 256, 0, stream>>>(cs);
    convert_kernel<<<(XN + 4 * WN) / 4 / 256, 256, 0, stream>>>(x, w_q, w_k, w_v, w_o, Xbf, Wbf);

    dim3 ggrid(MTOT / BM, D_MODEL / BN);
    gemm_bf16_kernel<0, 1><<<ggrid, 256, 0, stream>>>(Xbf, Wbf + 0 * (size_t)WN, b_q, Qbf);
    gemm_bf16_kernel<0, 1><<<ggrid, 256, 0, stream>>>(Xbf, Wbf + 1 * (size_t)WN, b_k, Kbf);
    gemm_bf16_kernel<0, 2><<<ggrid, 256, 0, stream>>>(Xbf, Wbf + 2 * (size_t)WN, b_v, VTbf);

    rope_kernel<<<(BATCH * NHEADS * SEQ * 8 + 255) / 256, 256, 0, stream>>>(Qbf, Kbf, cs);

    attn_mfma_kernel<<<dim3(SEQ / AQT, BATCH * NHEADS), 256, 0, stream>>>(Qbf, Kbf, VTbf);

    gemm_bf16_kernel<1, 0><<<ggrid, 256, 0, stream>>>(Qbf, Wbf + 3 * (size_t)WN, b_o, out);
}

// Round 13
// 477.604 us; speedup vs baseline: 6.1644x; 1.0646x over previous
//
#include <hip/hip_runtime.h>
#include <hip/hip_bf16.h>
#include <math.h>

// ---------------------------------------------------------------------------
// Round 13 (= round 12 resubmit after infra timeout):
// attention 32 q-rows/wave (2 M-fragments) — K/V LDS reads feed 2x/4x MFMAs,
// staging+barriers amortized 2x; setprio around MFMA clusters; Ps region
// (16 rows/wave) reused across fragments so LDS stays 74.75 KB (2 blocks/CU).
// Pipeline (dbuf + counted vmcnt) unchanged from round 11.
// GEMMs unchanged (m97 structure; CMODE2 emits V^T).
// ws: Qbf | Kbf | VTbf | Xbf | Wbf(4) | cs  == 101,711,872 B
// ---------------------------------------------------------------------------

#define D_MODEL 2048
#define NHEADS  16
#define DK      128
#define BATCH   2
#define SEQ     2048
#define MTOT    (BATCH*SEQ)            // 4096
#define XN      (MTOT*D_MODEL)         // 8,388,608
#define WN      (D_MODEL*D_MODEL)      // 4,194,304

typedef __attribute__((ext_vector_type(8))) short bf16x8;
typedef __attribute__((ext_vector_type(4))) float f32x4;
typedef __attribute__((ext_vector_type(8))) unsigned short u16x8;

__device__ __forceinline__ float bf2f(unsigned short u) {
    union { unsigned int i; float f; } v; v.i = ((unsigned int)u) << 16; return v.f;
}
__device__ __forceinline__ unsigned short f2bfu(float f) {
    __hip_bfloat16 h = __float2bfloat16(f);   // RNE
    return *reinterpret_cast<unsigned short*>(&h);
}
__device__ __forceinline__ void async_copy16(const unsigned short* g, unsigned short* l) {
    __builtin_amdgcn_global_load_lds((const __attribute__((address_space(1))) void*)g,
                                     (__attribute__((address_space(3))) void*)l, 16, 0, 0);
}

// ---------------- RoPE cos/sin table
__global__ void rope_table_kernel(float2* __restrict__ cs) {
    int idx = blockIdx.x * blockDim.x + threadIdx.x;
    if (idx >= SEQ * 64) return;
    int s = idx >> 6, j = idx & 63;
    double inv = pow(10000.0, -(double)j / 64.0);
    double f = (double)s * inv;
    cs[idx] = make_float2((float)cos(f), (float)sin(f));
}

// ---------------- fp32 -> bf16 conversion of x and the 4 weights
__global__ void convert_kernel(const float* __restrict__ x,
                               const float* __restrict__ wq, const float* __restrict__ wk,
                               const float* __restrict__ wv, const float* __restrict__ wo,
                               unsigned short* __restrict__ Xbf, unsigned short* __restrict__ Wbf) {
    size_t e = ((size_t)blockIdx.x * blockDim.x + threadIdx.x) * 4;
    const float* src; unsigned short* dst;
    if (e < XN) { src = x + e; dst = Xbf + e; }
    else {
        size_t r = e - XN; int w = (int)(r >> 22); size_t o = r & (WN - 1);
        src = (w == 0 ? wq : w == 1 ? wk : w == 2 ? wv : wo) + o;
        dst = Wbf + (size_t)w * WN + o;
    }
    float4 v = *(const float4*)src;
    ushort4 u;
    u.x = f2bfu(v.x); u.y = f2bfu(v.y); u.z = f2bfu(v.z); u.w = f2bfu(v.w);
    *(ushort4*)dst = u;
}

// ---------------- bf16 MFMA GEMM: C[M=4096][N=2048] = A*W^T + bias, K=2048
// AMODE 0: A row-major bf16.  AMODE 1: A head-major bf16 [B][H][S][DK].
// CMODE 0: C fp32 row-major.  CMODE 1: C bf16 head-major [B][H][S][DK].
// CMODE 2: C bf16 head-major TRANSPOSED [B][H][DK][S]  (for V^T).
#define BM 128
#define BN 128
#define BK 32

template<int AMODE, int CMODE>
__global__ __launch_bounds__(256, 2)
void gemm_bf16_kernel(const unsigned short* __restrict__ A,
                      const unsigned short* __restrict__ W,
                      const float* __restrict__ bias, void* __restrict__ Cout) {
    __shared__ unsigned short smem[8704];   // K-loop: As[128][32]|Bs[128][32]; CMODE2 epilogue: [128][68]
    const int tid = threadIdx.x;
    const int lane = tid & 63, wid = tid >> 6;
    const int wm = wid >> 1, wn = wid & 1;
    const int m0 = blockIdx.x * BM, n0 = blockIdx.y * BN;

    f32x4 acc[4][4];
    #pragma unroll
    for (int i = 0; i < 4; ++i)
        #pragma unroll
        for (int j = 0; j < 4; ++j) acc[i][j] = (f32x4){0.f, 0.f, 0.f, 0.f};

    const int lrow = lane & 15, lkc = lane >> 4;

    for (int k0 = 0; k0 < D_MODEL; k0 += BK) {
        #pragma unroll
        for (int i = 0; i < 4; ++i) {
            const int off = i * 4096 + wid * 1024 + lane * 16;   // byte in 16KB tile-pair
            const unsigned short* src;
            if (i < 2) {                          // A region [0,8192)
                int elem = off >> 1, row = elem >> 5, col = elem & 31;
                if (AMODE == 0) {
                    src = A + (size_t)(m0 + row) * D_MODEL + k0 + col;
                } else {
                    int m = m0 + row, b = m >> 11, s = m & 2047;
                    src = A + (((size_t)(b * NHEADS + (k0 >> 7))) * SEQ + s) * DK + (k0 & 127) + col;
                }
            } else {                              // B region
                int elem = (off - 8192) >> 1, row = elem >> 5, col = elem & 31;
                src = W + (size_t)(n0 + row) * D_MODEL + k0 + col;
            }
            async_copy16(src, &smem[(i * 4096 + wid * 1024) >> 1]);  // wave-uniform dest
        }
        __syncthreads();

        bf16x8 a[4], b[4];
        #pragma unroll
        for (int mi = 0; mi < 4; ++mi)
            a[mi] = *(const bf16x8*)&smem[(wm * 64 + mi * 16 + lrow) * 32 + lkc * 8];
        #pragma unroll
        for (int ni = 0; ni < 4; ++ni)
            b[ni] = *(const bf16x8*)&smem[4096 + (wn * 64 + ni * 16 + lrow) * 32 + lkc * 8];
        #pragma unroll
        for (int mi = 0; mi < 4; ++mi)
            #pragma unroll
            for (int ni = 0; ni < 4; ++ni)
                acc[mi][ni] = __builtin_amdgcn_mfma_f32_16x16x32_bf16(a[mi], b[ni], acc[mi][ni], 0, 0, 0);
        __syncthreads();
    }

    // epilogue: C/D layout col=lane&15, row=(lane>>4)*4+r  [m89-verified]
    const int lq = lane >> 4;
    if (CMODE != 2) {
        #pragma unroll
        for (int ni = 0; ni < 4; ++ni) {
            int col = n0 + wn * 64 + ni * 16 + lrow;
            float bv = bias[col];
            #pragma unroll
            for (int mi = 0; mi < 4; ++mi) {
                #pragma unroll
                for (int r = 0; r < 4; ++r) {
                    int row = m0 + wm * 64 + mi * 16 + lq * 4 + r;
                    float v = acc[mi][ni][r] + bv;
                    if (CMODE == 0) {
                        ((float*)Cout)[(size_t)row * D_MODEL + col] = v;
                    } else {
                        int bb = row >> 11, s = row & 2047, h = col >> 7, d = col & 127;
                        ((unsigned short*)Cout)[(((size_t)(bb * NHEADS + h)) * SEQ + s) * DK + d] = f2bfu(v);
                    }
                }
            }
        }
    } else {
        // CMODE 2: write C^T head-major: VT[b][h][d][s].  BN==128==DK, so
        // h = n0>>7 and d = local col.  LDS-transpose in two 64-col halves.
        const int b = m0 >> 11;
        const int h = n0 >> 7;
        const int sbase = m0 & 2047;
        unsigned short* vtbase = (unsigned short*)Cout +
            (((size_t)(b * NHEADS + h)) * DK) * SEQ + sbase;
        #pragma unroll
        for (int half = 0; half < 2; ++half) {
            __syncthreads();
            if (wn == half) {
                #pragma unroll
                for (int ni = 0; ni < 4; ++ni) {
                    float bv = bias[n0 + half * 64 + ni * 16 + lrow];
                    #pragma unroll
                    for (int mi = 0; mi < 4; ++mi)
                        #pragma unroll
                        for (int r = 0; r < 4; ++r) {
                            int row = wm * 64 + mi * 16 + lq * 4 + r;
                            smem[row * 68 + ni * 16 + lrow] = f2bfu(acc[mi][ni][r] + bv);
                        }
                }
            }
            __syncthreads();
            // read transposed: thread -> d = half*64 + (tid>>2), s-chunk (tid&3)*32
            int dl = tid >> 2, s0 = (tid & 3) * 32;
            u16x8 o[4];
            #pragma unroll
            for (int j8 = 0; j8 < 4; ++j8)
                #pragma unroll
                for (int j = 0; j < 8; ++j)
                    o[j8][j] = smem[(s0 + j8 * 8 + j) * 68 + dl];
            unsigned short* dst = vtbase + (size_t)(half * 64 + dl) * SEQ + s0;
            #pragma unroll
            for (int j8 = 0; j8 < 4; ++j8)
                *(u16x8*)(dst + j8 * 8) = o[j8];
        }
    }
}

// ---------------- in-place RoPE on bf16 Q and K; Q additionally scaled 1/sqrt(DK)
__global__ void rope_kernel(unsigned short* __restrict__ Q, unsigned short* __restrict__ Kt,
                            const float2* __restrict__ cs) {
    const float qscale = 0.08838834764831845f;   // 1/sqrt(128), folded into Q
    int idx = blockIdx.x * blockDim.x + threadIdx.x;   // B*H*S*8
    if (idx >= BATCH * NHEADS * SEQ * 8) return;
    int j8 = idx & 7, bhs = idx >> 3, s = bhs & (SEQ - 1);
    int d0 = j8 * 8;
    size_t base = (size_t)bhs * DK;
    u16x8 qlo = *(const u16x8*)(Q + base + d0);
    u16x8 qhi = *(const u16x8*)(Q + base + 64 + d0);
    u16x8 klo = *(const u16x8*)(Kt + base + d0);
    u16x8 khi = *(const u16x8*)(Kt + base + 64 + d0);
    u16x8 olo, ohi, plo, phi;
    #pragma unroll
    for (int j = 0; j < 8; ++j) {
        float2 c = cs[(s << 6) + d0 + j];
        float q0 = bf2f(qlo[j]), q1 = bf2f(qhi[j]);
        olo[j] = f2bfu((q0 * c.x - q1 * c.y) * qscale);
        ohi[j] = f2bfu((q1 * c.x + q0 * c.y) * qscale);
        float k0 = bf2f(klo[j]), k1 = bf2f(khi[j]);
        plo[j] = f2bfu(k0 * c.x - k1 * c.y);
        phi[j] = f2bfu(k1 * c.x + k0 * c.y);
    }
    *(u16x8*)(Q + base + d0) = olo;
    *(u16x8*)(Q + base + 64 + d0) = ohi;
    *(u16x8*)(Kt + base + d0) = plo;
    *(u16x8*)(Kt + base + 64 + d0) = phi;
}

// ---------------- bf16 MFMA flash attention; O (bf16) overwrites Q panel
// 4 waves x 32 q-rows (2 M-fragments of 16); KT=64; K and V^T staged via
// global_load_lds (pre-swizzled sources), double-buffered, counted vmcnt.
// Each Ks read feeds 2 MFMAs, each Vs read feeds 4 MFMAs. Ps (16 rows/wave)
// is written/read per-fragment (same-wave DS ordering makes reuse safe).
#define AQT 128
#define AKT 64
#define NT  (SEQ/AKT)
#define PSS 72

__global__ __launch_bounds__(256, 2)
void attn_mfma_kernel(unsigned short* __restrict__ Q,
                      const unsigned short* __restrict__ Kp,
                      const unsigned short* __restrict__ VTp) {
    __shared__ unsigned short Ks[2][AKT * DK];   // 2 x 16 KB, row-swizzled
    __shared__ unsigned short Vs[2][DK * AKT];   // 2 x 16 KB, [d][kk] chunk-swizzled
    __shared__ unsigned short Ps[64 * PSS];      // 9216 B, 16 rows per wave (reused per frag)
    const int tid = threadIdx.x;
    const int lane = tid & 63, wid = tid >> 6;
    const int lrow = lane & 15, lkc = lane >> 4;
    const int bh = blockIdx.y;
    const int q0 = blockIdx.x * AQT;
    unsigned short* qpanel = Q + (size_t)bh * SEQ * DK;
    const unsigned short* kpanel  = Kp  + (size_t)bh * SEQ * DK;
    const unsigned short* vtpanel = VTp + (size_t)bh * DK * SEQ;

    // Q fragments: 2 row-groups x 4 k-chunks, registers all loop (pre-scaled)
    bf16x8 qfrag[2][4];
    #pragma unroll
    for (int f = 0; f < 2; ++f) {
        const unsigned short* qsrc =
            qpanel + (size_t)(q0 + wid * 32 + f * 16 + lrow) * DK + lkc * 8;
        #pragma unroll
        for (int c = 0; c < 4; ++c)
            qfrag[f][c] = *(const bf16x8*)(qsrc + c * 32);
    }

    // staging: 8 global_load_lds per wave per tile (4 K + 4 V)
    const int st_elem = wid * 512 + lane * 8;
    const int k_row = st_elem >> 7;
    const int k_colS = (st_elem & 127);
    const int v_d = st_elem >> 6;
    const int v_c = (st_elem >> 3) & 7;

#define STAGE(tt, bb)                                                                   \
    {                                                                                   \
        int kv0 = (tt) * AKT;                                                           \
        _Pragma("unroll")                                                               \
        for (int i = 0; i < 4; ++i) {                                                   \
            int row = i * 16 + k_row;                                                   \
            int colS = k_colS ^ ((row & 7) << 3);                                       \
            async_copy16(kpanel + (size_t)(kv0 + row) * DK + colS,                      \
                         &Ks[bb][i * 2048 + wid * 512]);                                \
        }                                                                               \
        _Pragma("unroll")                                                               \
        for (int i = 0; i < 4; ++i) {                                                   \
            int d = i * 32 + v_d;                                                       \
            int cS = v_c ^ (d & 7);                                                     \
            async_copy16(vtpanel + (size_t)d * SEQ + kv0 + cS * 8,                      \
                         &Vs[bb][i * 2048 + wid * 512]);                                \
        }                                                                               \
    }

    float m_i[2][4], l_i[2][4];
    f32x4 oacc[2][8];
    #pragma unroll
    for (int f = 0; f < 2; ++f) {
        #pragma unroll
        for (int r = 0; r < 4; ++r) { m_i[f][r] = -1e30f; l_i[f][r] = 0.f; }
        #pragma unroll
        for (int dt = 0; dt < 8; ++dt) oacc[f][dt] = (f32x4){0.f, 0.f, 0.f, 0.f};
    }

    STAGE(0, 0);
    int buf = 0;

    for (int tt = 0; tt < NT; ++tt) {
        if (tt + 1 < NT) {
            STAGE(tt + 1, buf ^ 1);
            asm volatile("s_waitcnt vmcnt(8)" ::: "memory");   // tile tt's 8 loads done
        } else {
            asm volatile("s_waitcnt vmcnt(0)" ::: "memory");
        }
        __builtin_amdgcn_sched_barrier(0);
        __builtin_amdgcn_s_barrier();                          // tile tt visible to all

        const unsigned short* KsB = Ks[buf];
        const unsigned short* VsB = Vs[buf];

        // ---- QK^T: each kf read feeds both row-fragments (32 MFMA total)
        f32x4 sacc[2][4];
        #pragma unroll
        for (int f = 0; f < 2; ++f)
            #pragma unroll
            for (int t = 0; t < 4; ++t) sacc[f][t] = (f32x4){0.f, 0.f, 0.f, 0.f};
        __builtin_amdgcn_s_setprio(1);
        #pragma unroll
        for (int t = 0; t < 4; ++t) {
            int krl = t * 16 + lrow;
            int sw = (krl & 7) << 3;
            #pragma unroll
            for (int c = 0; c < 4; ++c) {
                bf16x8 kf = *(const bf16x8*)&KsB[(krl * DK + c * 32 + lkc * 8) ^ sw];
                sacc[0][t] = __builtin_amdgcn_mfma_f32_16x16x32_bf16(qfrag[0][c], kf, sacc[0][t], 0, 0, 0);
                sacc[1][t] = __builtin_amdgcn_mfma_f32_16x16x32_bf16(qfrag[1][c], kf, sacc[1][t], 0, 0, 0);
            }
        }
        __builtin_amdgcn_s_setprio(0);

        // ---- per-fragment softmax + Ps round-trip (wave-private 16 rows, reused)
        bf16x8 pf[2][2];
        #pragma unroll
        for (int f = 0; f < 2; ++f) {
            float mx[4];
            #pragma unroll
            for (int r = 0; r < 4; ++r) {
                float v = fmaxf(fmaxf(sacc[f][0][r], sacc[f][1][r]),
                                fmaxf(sacc[f][2][r], sacc[f][3][r]));
                #pragma unroll
                for (int off = 1; off <= 8; off <<= 1)
                    v = fmaxf(v, __shfl_xor(v, off, 64));
                mx[r] = v;
            }
            int cond = (mx[0] - m_i[f][0] <= 8.f) && (mx[1] - m_i[f][1] <= 8.f) &&
                       (mx[2] - m_i[f][2] <= 8.f) && (mx[3] - m_i[f][3] <= 8.f);
            if (!__all(cond)) {
                #pragma unroll
                for (int r = 0; r < 4; ++r) {
                    float mnew = fmaxf(m_i[f][r], mx[r]);
                    float corr = __expf(m_i[f][r] - mnew);
                    l_i[f][r] *= corr;
                    #pragma unroll
                    for (int dt = 0; dt < 8; ++dt) oacc[f][dt][r] *= corr;
                    m_i[f][r] = mnew;
                }
            }
            #pragma unroll
            for (int r = 0; r < 4; ++r) {
                float p0 = __expf(sacc[f][0][r] - m_i[f][r]);
                float p1 = __expf(sacc[f][1][r] - m_i[f][r]);
                float p2 = __expf(sacc[f][2][r] - m_i[f][r]);
                float p3 = __expf(sacc[f][3][r] - m_i[f][r]);
                float rs = (p0 + p1) + (p2 + p3);
                #pragma unroll
                for (int off = 1; off <= 8; off <<= 1)
                    rs += __shfl_xor(rs, off, 64);
                l_i[f][r] += rs;
                int pb = (wid * 16 + lkc * 4 + r) * PSS;
                Ps[pb + lrow]      = f2bfu(p0);
                Ps[pb + 16 + lrow] = f2bfu(p1);
                Ps[pb + 32 + lrow] = f2bfu(p2);
                Ps[pb + 48 + lrow] = f2bfu(p3);
            }
            const int arow = (wid * 16 + lrow) * PSS;
            pf[f][0] = *(const bf16x8*)&Ps[arow + lkc * 8];
            pf[f][1] = *(const bf16x8*)&Ps[arow + 32 + lkc * 8];
        }

        // ---- PV: each V read feeds 4 MFMAs (32 MFMA total)
        __builtin_amdgcn_s_setprio(1);
        #pragma unroll
        for (int dt = 0; dt < 8; ++dt) {
            int d = dt * 16 + lrow;
            int basev = d * 64;
            bf16x8 vfA = *(const bf16x8*)&VsB[basev + ((lkc     ^ (lrow & 7)) * 8)];
            bf16x8 vfB = *(const bf16x8*)&VsB[basev + (((lkc+4) ^ (lrow & 7)) * 8)];
            oacc[0][dt] = __builtin_amdgcn_mfma_f32_16x16x32_bf16(pf[0][0], vfA, oacc[0][dt], 0, 0, 0);
            oacc[0][dt] = __builtin_amdgcn_mfma_f32_16x16x32_bf16(pf[0][1], vfB, oacc[0][dt], 0, 0, 0);
            oacc[1][dt] = __builtin_amdgcn_mfma_f32_16x16x32_bf16(pf[1][0], vfA, oacc[1][dt], 0, 0, 0);
            oacc[1][dt] = __builtin_amdgcn_mfma_f32_16x16x32_bf16(pf[1][1], vfB, oacc[1][dt], 0, 0, 0);
        }
        __builtin_amdgcn_s_setprio(0);

        asm volatile("s_waitcnt lgkmcnt(0)" ::: "memory");     // LDS reads drained
        __builtin_amdgcn_sched_barrier(0);
        __builtin_amdgcn_s_barrier();                          // safe to overwrite buf^1
        buf ^= 1;
    }
#undef STAGE

    // ---- normalize + write O (bf16) over own Q rows
    #pragma unroll
    for (int f = 0; f < 2; ++f) {
        float inv[4];
        #pragma unroll
        for (int r = 0; r < 4; ++r) inv[r] = 1.0f / l_i[f][r];
        #pragma unroll
        for (int dt = 0; dt < 8; ++dt) {
            #pragma unroll
            for (int r = 0; r < 4; ++r) {
                int q = q0 + wid * 32 + f * 16 + lkc * 4 + r;
                qpanel[(size_t)q * DK + dt * 16 + lrow] = f2bfu(oacc[f][dt][r] * inv[r]);
            }
        }
    }
}

// ---------------------------------------------------------------------------
extern "C" void kernel_launch(void* const* d_in, const int* in_sizes, int n_in,
                              void* d_out, int out_size, void* d_ws, size_t ws_size,
                              hipStream_t stream) {
    const float* x   = (const float*)d_in[0];
    const float* w_q = (const float*)d_in[1];
    const float* b_q = (const float*)d_in[2];
    const float* w_k = (const float*)d_in[3];
    const float* b_k = (const float*)d_in[4];
    const float* w_v = (const float*)d_in[5];
    const float* b_v = (const float*)d_in[6];
    const float* w_o = (const float*)d_in[7];
    const float* b_o = (const float*)d_in[8];
    float* out = (float*)d_out;

    char* ws = (char*)d_ws;
    const size_t bfTensor = (size_t)BATCH * NHEADS * SEQ * DK * 2;   // 16,777,216 B
    unsigned short* Qbf  = (unsigned short*)(ws);
    unsigned short* Kbf  = (unsigned short*)(ws + bfTensor);
    unsigned short* VTbf = (unsigned short*)(ws + 2 * bfTensor);     // [b][h][d][s]
    unsigned short* Xbf  = (unsigned short*)(ws + 3 * bfTensor);
    unsigned short* Wbf  = (unsigned short*)(ws + 4 * bfTensor);     // 4 weights
    float2*         cs   = (float2*)(ws + 6 * bfTensor);             // 1 MB
    // total = 6*16.78MB + 1MB = 101,711,872 B

    rope_table_kernel<<<(SEQ * 64 + 255) / 256, 256, 0, stream>>>(cs);
    convert_kernel<<<(XN + 4 * WN) / 4 / 256, 256, 0, stream>>>(x, w_q, w_k, w_v, w_o, Xbf, Wbf);

    dim3 ggrid(MTOT / BM, D_MODEL / BN);
    gemm_bf16_kernel<0, 1><<<ggrid, 256, 0, stream>>>(Xbf, Wbf + 0 * (size_t)WN, b_q, Qbf);
    gemm_bf16_kernel<0, 1><<<ggrid, 256, 0, stream>>>(Xbf, Wbf + 1 * (size_t)WN, b_k, Kbf);
    gemm_bf16_kernel<0, 2><<<ggrid, 256, 0, stream>>>(Xbf, Wbf + 2 * (size_t)WN, b_v, VTbf);

    rope_kernel<<<(BATCH * NHEADS * SEQ * 8 + 255) / 256, 256, 0, stream>>>(Qbf, Kbf, cs);

    attn_mfma_kernel<<<dim3(SEQ / AQT, BATCH * NHEADS), 256, 0, stream>>>(Qbf, Kbf, VTbf);

    gemm_bf16_kernel<1, 0><<<ggrid, 256, 0, stream>>>(Qbf, Wbf + 3 * (size_t)WN, b_o, out);
}